// Round 9
// baseline (297.060 us; speedup 1.0000x reference)
//
#include <hip/hip_runtime.h>
#include <math.h>

#define DIM     768
#define NH      12
#define HD      64
#define NTOK    1025
#define NTOKP   1088                  // padded tokens (17*64) for Q/K/V bufs
#define BATCH   16
#define MTOT    (BATCH * NTOK)        // 16400
#define QKVD    (3 * DIM)             // 2304

typedef short  short8 __attribute__((ext_vector_type(8)));
typedef float  f32x4  __attribute__((ext_vector_type(4)));

typedef const __attribute__((address_space(1))) void gvoid_t;
typedef __attribute__((address_space(3)))       void lvoid_t;
#define GLD16(gsrc, ldst) __builtin_amdgcn_global_load_lds( \
    (gvoid_t*)(gsrc), (lvoid_t*)(ldst), 16, 0, 0)

static __device__ __forceinline__ unsigned int f2bf(float f) {
    unsigned int u = __float_as_uint(f);
    u += 0x7FFFu + ((u >> 16) & 1u);      // RNE
    return u >> 16;
}

static __device__ __forceinline__ float red_sum(float x) {
    x += __shfl_xor(x, 16);
    x += __shfl_xor(x, 32);
    return x;
}

// ------------------------------------------------------------------
// Kernel 0: fp32 -> bf16 conversion of x, W_qkv, W_proj
// ------------------------------------------------------------------
__device__ __forceinline__ void cvt8(const float* __restrict__ src,
                                     unsigned short* __restrict__ dst, int i) {
    float4 a = *(const float4*)(src + (size_t)i*8);
    float4 b = *(const float4*)(src + (size_t)i*8 + 4);
    uint4 pk;
    pk.x = f2bf(a.x) | (f2bf(a.y) << 16);
    pk.y = f2bf(a.z) | (f2bf(a.w) << 16);
    pk.z = f2bf(b.x) | (f2bf(b.y) << 16);
    pk.w = f2bf(b.z) | (f2bf(b.w) << 16);
    *(uint4*)(dst + (size_t)i*8) = pk;
}

__global__ __launch_bounds__(256) void cvt_bf16_kernel(
    const float* __restrict__ x, const float* __restrict__ Wq,
    const float* __restrict__ Wp,
    unsigned short* __restrict__ xb, unsigned short* __restrict__ Wqb,
    unsigned short* __restrict__ Wpb)
{
    const int stride = gridDim.x * blockDim.x;
    const int tid = blockIdx.x * blockDim.x + threadIdx.x;
    for (int i = tid; i < MTOT*DIM/8;  i += stride) cvt8(x,  xb,  i);
    for (int i = tid; i < QKVD*DIM/8;  i += stride) cvt8(Wq, Wqb, i);
    for (int i = tid; i < DIM*DIM/8;   i += stride) cvt8(Wp, Wpb, i);
}

// ------------------------------------------------------------------
// Kernel 0b: RoPE cos/sin table  [h][n1][pair] float2, 393216 entries
// ------------------------------------------------------------------
__global__ __launch_bounds__(256) void rope_tab_kernel(
    const float* __restrict__ freqs, float2* __restrict__ tab)
{
    const int gid = blockIdx.x * 256 + threadIdx.x;     // < 393216
    const int p  = gid & 31;
    const int n1 = (gid >> 5) & 1023;
    const int h  = gid >> 15;
    const float tx = (float)(n1 & 31), ty = (float)(n1 >> 5);
    const float ang = tx * freqs[h*32 + p] + ty * freqs[384 + h*32 + p];
    float s, c;
    sincosf(ang, &s, &c);
    tab[gid] = make_float2(c, s);
}

// ------------------------------------------------------------------
// Kernel 0c: zero the token pad region [1025,1088) of Q/K/V.
// Zero K-pad => s=0 => p=1 (corrected by l-=63); zero V-pad => O+=0.
// grid 1134, block 256 (exact: 3 * 192 * 504 uint4).
// ------------------------------------------------------------------
__global__ __launch_bounds__(256) void pad_zero_kernel(
    unsigned short* __restrict__ Qb, unsigned short* __restrict__ Kb,
    unsigned short* __restrict__ Vb)
{
    const int gid   = blockIdx.x * 256 + threadIdx.x;   // < 290304
    const int which = gid / 96768;
    const int r     = gid - which * 96768;
    const int bh    = r / 504;                          // 63*64/8 per bh
    const int off   = r - bh * 504;
    unsigned short* p = (which == 0) ? Qb : (which == 1) ? Kb : Vb;
    *(uint4*)(p + ((size_t)bh*NTOKP + NTOK)*HD + off*8) = make_uint4(0,0,0,0);
}

// ------------------------------------------------------------------
// Shared bf16 MFMA GEMM core: C[feat][tok] = W[feat][k] * X[tok][k]^T
// K=768, tile 128x128, BK=64, 256 threads (4 waves 2x2, each 64x64).
// ------------------------------------------------------------------
__device__ __forceinline__ void gemm_core(
    const unsigned short* __restrict__ Wb,
    const unsigned short* __restrict__ Xb,
    int D0, int T0, int maxXrow,
    short* Ws, short* Xs, f32x4 acc[4][4], int tid)
{
    const int lane = tid & 63;
    const int wu   = __builtin_amdgcn_readfirstlane(tid >> 6);
    const int wr   = wu >> 1, wc = wu & 1;
    const int l4   = lane >> 4, l15 = lane & 15;

    const int srow = lane >> 3;
    const int schk = (lane & 7) ^ srow;
    const unsigned short* wsrc[4];
    const unsigned short* xsrc[4];
#pragma unroll
    for (int i = 0; i < 4; ++i) {
        int r = wu*32 + i*8 + srow;
        wsrc[i] = Wb + (size_t)(D0 + r) * DIM + schk*8;
        int xr = T0 + r; if (xr > maxXrow) xr = maxXrow;
        xsrc[i] = Xb + (size_t)xr * DIM + schk*8;
    }

    for (int kt = 0; kt < DIM/64; ++kt) {
        __syncthreads();
#pragma unroll
        for (int i = 0; i < 4; ++i) {
            GLD16(wsrc[i] + kt*64, &Ws[(wu*4 + i) * 512]);
            GLD16(xsrc[i] + kt*64, &Xs[(wu*4 + i) * 512]);
        }
        __syncthreads();

        short8 wf[4][2], xf[4][2];
#pragma unroll
        for (int f = 0; f < 4; ++f) {
            const int rw = wr*64 + f*16 + l15;
            const int rx = wc*64 + f*16 + l15;
#pragma unroll
            for (int kf = 0; kf < 2; ++kf) {
                wf[f][kf] = *(const short8*)&Ws[rw*64 + (((kf*4 + l4) ^ (rw & 7)) << 3)];
                xf[f][kf] = *(const short8*)&Xs[rx*64 + (((kf*4 + l4) ^ (rx & 7)) << 3)];
            }
        }
        __builtin_amdgcn_s_setprio(1);
#pragma unroll
        for (int kf = 0; kf < 2; ++kf)
#pragma unroll
            for (int fm = 0; fm < 4; ++fm)
#pragma unroll
                for (int fn = 0; fn < 4; ++fn)
                    acc[fm][fn] = __builtin_amdgcn_mfma_f32_16x16x32_bf16(
                        wf[fm][kf], xf[fn][kf], acc[fm][fn], 0, 0, 0);
        __builtin_amdgcn_s_setprio(0);
    }
}

// ------------------------------------------------------------------
// Kernel 1: QKV GEMM + fused RoPE (table), bf16 out to Q/K/V
// (B,H,NTOKP,64) padded layout. Q pre-scaled by scale*log2(e).
// grid (18, 129), block 256.
// ------------------------------------------------------------------
__global__ __launch_bounds__(256) void qkv_gemm_kernel(
    const unsigned short* __restrict__ Wqb, const unsigned short* __restrict__ xb,
    const float2* __restrict__ tab,
    unsigned short* __restrict__ Qb, unsigned short* __restrict__ Kb,
    unsigned short* __restrict__ Vb)
{
    __shared__ __align__(16) short Ws[128*64];
    __shared__ __align__(16) short Xs[128*64];
    f32x4 acc[4][4] = {};
    const int tid = threadIdx.x;
    const int D0 = blockIdx.x * 128;
    const int T0 = blockIdx.y * 128;
    gemm_core(Wqb, xb, D0, T0, MTOT - 1, Ws, Xs, acc, tid);

    const int lane = tid & 63;
    const int wu = tid >> 6, wr = wu >> 1, wc = wu & 1;
    const int l4 = lane >> 4, l15 = lane & 15;
    const int which = D0 / DIM;
    unsigned short* dst = (which == 0) ? Qb : (which == 1) ? Kb : Vb;
    const float qs = (which == 0) ? 0.125f * 1.44269504089f : 1.f;

    unsigned bArr[4], nArr[4];
    bool vArr[4];
#pragma unroll
    for (int fn = 0; fn < 4; ++fn) {
        unsigned m = T0 + wc*64 + fn*16 + l15;
        vArr[fn] = m < MTOT;
        bArr[fn] = m / NTOK;
        nArr[fn] = m - bArr[fn]*NTOK;
    }
#pragma unroll
    for (int fm = 0; fm < 4; ++fm) {
        const int hcol = (D0 % DIM) + wr*64 + fm*16 + l4*4;
        const int h = hcol >> 6, dd = hcol & 63;
        const int p0 = dd >> 1;                    // even
#pragma unroll
        for (int fn = 0; fn < 4; ++fn) {
            if (!vArr[fn]) continue;
            f32x4 a = acc[fm][fn];
            const int n = nArr[fn];
            if (which < 2) {                       // RoPE on Q,K (not CLS)
                int n1 = n > 0 ? n - 1 : 0;
                float4 cs = *(const float4*)&tab[(size_t)(h*1024 + n1)*32 + p0];
                if (n == 0) cs = make_float4(1.f, 0.f, 1.f, 0.f);
                float e0 = a[0], od0 = a[1], e1 = a[2], od1 = a[3];
                a[0] = e0*cs.x - od0*cs.y;  a[1] = e0*cs.y + od0*cs.x;
                a[2] = e1*cs.z - od1*cs.w;  a[3] = e1*cs.w + od1*cs.z;
            }
            uint2 pk;
            pk.x = f2bf(a[0]*qs) | (f2bf(a[1]*qs) << 16);
            pk.y = f2bf(a[2]*qs) | (f2bf(a[3]*qs) << 16);
            *(uint2*)&dst[((size_t)(bArr[fn]*NH + h)*NTOKP + n)*HD + dd] = pk;
        }
    }
}

// ------------------------------------------------------------------
// Kernel 2: bf16 MFMA flash attention, O^T, no max tracking, padded
// token domain (17 full tiles, no masks/clamps, l -= 63 exact fix).
// Double-buffered K/V, one barrier/tile, running global pointers.
// grid 1728 XCD-chunked, block 256 (4 waves, 32q each).
// ------------------------------------------------------------------
__global__ __launch_bounds__(256) void attn_mfma_kernel(
    const unsigned short* __restrict__ Qb,
    const unsigned short* __restrict__ Kb,
    const unsigned short* __restrict__ Vb,
    unsigned short* __restrict__ Obf)
{
    __shared__ __align__(16) char KsR[2*8192];   // [buf][64tok][64d], chunk^(tok&7)
    __shared__ __align__(16) char VtR[2*8192];   // [buf][64d][64tok], chunk^(d&7)
    __shared__ __align__(16) char PsR[4][4096];  // per wave [32q][64tok], swz

    const int tid  = threadIdx.x;
    const int lane = tid & 63;
    const int w    = __builtin_amdgcn_readfirstlane(tid >> 6);
    const int l4   = lane >> 4, l15 = lane & 15, l7 = lane & 7;

    const int d    = blockIdx.x;
    const int xcd  = d & 7;
    const int s    = d >> 3;                 // 0..215
    const int bh   = xcd * 24 + s / 9;
    const int q0   = (s % 9) * 128;
    const size_t base = (size_t)bh * NTOKP * HD;

    // Q frags (pre-scaled); clamp only here (prologue, not hot loop)
    short8 qf[2][2];
#pragma unroll
    for (int qg = 0; qg < 2; ++qg) {
        int qr = q0 + w*32 + qg*16 + l15;
        int qrc = qr < NTOK ? qr : NTOK - 1;
        qf[qg][0] = *(const short8*)(Qb + base + (size_t)qrc*HD + l4*8);
        qf[qg][1] = *(const short8*)(Qb + base + (size_t)qrc*HD + 32 + l4*8);
    }

    float lA = 0.f, lB = 0.f;
    f32x4 oA[4] = {}, oB[4] = {};          // O^T: row=d (l4,r), col=q (l15)

    const int ktokb = tid >> 3;                  // 0..31
    const int kchk  = tid & 7;
    const int vtok  = ((tid & 7) << 3) | ((tid >> 3) & 7);
    const int vc    = vtok >> 3;
    const int vb2   = (vtok & 7) * 2;
    char* Pw = &PsR[w][0];

    // running global pointers (advance 64*HD = 4096 elems per tile)
    const unsigned short* kp0 = Kb + base + (size_t)ktokb*HD
                                + (size_t)(kchk ^ (ktokb & 7))*8;
    const unsigned short* kp1 = kp0 + 32*HD;
    const unsigned short* vp  = Vb + base + (size_t)vtok*HD + w*8;

    // ---- prologue: stage tile 0, preload V(1) regs ----
    GLD16(kp0, KsR + w*1024);
    GLD16(kp1, KsR + 4096 + w*1024);
    kp0 += 4096; kp1 += 4096;

    uint4 vg[2];
    vg[0] = *(const uint4*)vp;
    vg[1] = *(const uint4*)(vp + 32);
    vp += 4096;
#pragma unroll
    for (int i = 0; i < 2; ++i) {          // V(0) -> VtR buf0
        const int vd0 = w*8 + i*32;
        unsigned short vs[8];
        vs[0]=(unsigned short)vg[i].x; vs[1]=(unsigned short)(vg[i].x>>16);
        vs[2]=(unsigned short)vg[i].y; vs[3]=(unsigned short)(vg[i].y>>16);
        vs[4]=(unsigned short)vg[i].z; vs[5]=(unsigned short)(vg[i].z>>16);
        vs[6]=(unsigned short)vg[i].w; vs[7]=(unsigned short)(vg[i].w>>16);
#pragma unroll
        for (int j = 0; j < 8; ++j)
            *(unsigned short*)(VtR + (vd0+j)*128 + ((vc ^ j) << 4) + vb2) = vs[j];
    }
    vg[0] = *(const uint4*)vp;             // V(1)
    vg[1] = *(const uint4*)(vp + 32);
    vp += 4096;

    for (int kt = 0; kt < 17; ++kt) {
        const int buf = kt & 1;
        const char* Kc = KsR + buf*8192;
        const char* Vc = VtR + buf*8192;
        __syncthreads();   // tile kt staged & visible

        if (kt < 16) {
            char* kd = KsR + (buf^1)*8192 + w*1024;
            GLD16(kp0, kd);
            GLD16(kp1, kd + 4096);
            kp0 += 4096; kp1 += 4096;
            char* vd = VtR + (buf^1)*8192;
#pragma unroll
            for (int i = 0; i < 2; ++i) {  // V(kt+1) -> VtR[nb]
                const int vd0 = w*8 + i*32;
                unsigned short vs[8];
                vs[0]=(unsigned short)vg[i].x; vs[1]=(unsigned short)(vg[i].x>>16);
                vs[2]=(unsigned short)vg[i].y; vs[3]=(unsigned short)(vg[i].y>>16);
                vs[4]=(unsigned short)vg[i].z; vs[5]=(unsigned short)(vg[i].z>>16);
                vs[6]=(unsigned short)vg[i].w; vs[7]=(unsigned short)(vg[i].w>>16);
#pragma unroll
                for (int j = 0; j < 8; ++j)
                    *(unsigned short*)(vd + (vd0+j)*128 + ((vc ^ j) << 4) + vb2) = vs[j];
            }
            if (kt < 15) {                 // V(kt+2) regs (pad ends at 1088)
                vg[0] = *(const uint4*)vp;
                vg[1] = *(const uint4*)(vp + 32);
                vp += 4096;
            }
        }

        // ---- S^T = K @ Q^T  (lane: q = l15, tok = tg*16 + l4*4 + r) ----
        f32x4 sA[4] = {}, sB[4] = {};
        __builtin_amdgcn_s_setprio(1);
#pragma unroll
        for (int tg = 0; tg < 4; ++tg) {
            const int row = tg*16 + l15;
            short8 ka0 = *(const short8*)(Kc + row*128 + ((l4 ^ l7) << 4));
            short8 ka1 = *(const short8*)(Kc + row*128 + (((4 + l4) ^ l7) << 4));
            sA[tg] = __builtin_amdgcn_mfma_f32_16x16x32_bf16(ka0, qf[0][0], sA[tg], 0,0,0);
            sA[tg] = __builtin_amdgcn_mfma_f32_16x16x32_bf16(ka1, qf[0][1], sA[tg], 0,0,0);
            sB[tg] = __builtin_amdgcn_mfma_f32_16x16x32_bf16(ka0, qf[1][0], sB[tg], 0,0,0);
            sB[tg] = __builtin_amdgcn_mfma_f32_16x16x32_bf16(ka1, qf[1][1], sB[tg], 0,0,0);
        }
        __builtin_amdgcn_s_setprio(0);

        // ---- p = exp2(s), no masks (pad tokens give p=1, fixed later) ----
        float pA[16], pB[16];
        float psA = 0.f, psB = 0.f;
#pragma unroll
        for (int tg = 0; tg < 4; ++tg)
#pragma unroll
            for (int r = 0; r < 4; ++r) {
                pA[tg*4+r] = __builtin_exp2f(sA[tg][r]); psA += pA[tg*4+r];
                pB[tg*4+r] = __builtin_exp2f(sB[tg][r]); psB += pB[tg*4+r];
            }
        lA += psA;   // lane-local; reduced once after the loop
        lB += psB;

        // ---- P -> LDS (packed bf16 pairs, b64 writes, swizzled) ----
#pragma unroll
        for (int tg = 0; tg < 4; ++tg) {
            unsigned k0a, k1a, k0b, k1b;
            asm volatile("v_cvt_pk_bf16_f32 %0, %1, %2" : "=v"(k0a) : "v"(pA[tg*4+0]), "v"(pA[tg*4+1]));
            asm volatile("v_cvt_pk_bf16_f32 %0, %1, %2" : "=v"(k1a) : "v"(pA[tg*4+2]), "v"(pA[tg*4+3]));
            asm volatile("v_cvt_pk_bf16_f32 %0, %1, %2" : "=v"(k0b) : "v"(pB[tg*4+0]), "v"(pB[tg*4+1]));
            asm volatile("v_cvt_pk_bf16_f32 %0, %1, %2" : "=v"(k1b) : "v"(pB[tg*4+2]), "v"(pB[tg*4+3]));
            const int chk = (((tg*2 + (l4 >> 1)) ^ l7) << 4) + (l4 & 1)*8;
            *(uint2*)(Pw + l15*128      + chk) = make_uint2(k0a, k1a);
            *(uint2*)(Pw + (16+l15)*128 + chk) = make_uint2(k0b, k1b);
        }
        __builtin_amdgcn_wave_barrier();

        const short8 pf00 = *(const short8*)(Pw + l15*128      + ((l4 ^ l7) << 4));
        const short8 pf01 = *(const short8*)(Pw + l15*128      + (((4+l4) ^ l7) << 4));
        const short8 pf10 = *(const short8*)(Pw + (16+l15)*128 + ((l4 ^ l7) << 4));
        const short8 pf11 = *(const short8*)(Pw + (16+l15)*128 + (((4+l4) ^ l7) << 4));

        // ---- O^T += V^T @ P ----
        __builtin_amdgcn_s_setprio(1);
#pragma unroll
        for (int dg = 0; dg < 4; ++dg) {
            const int dd = dg*16 + l15;
            short8 v0 = *(const short8*)(Vc + dd*128 + ((l4 ^ (dd & 7)) << 4));
            short8 v1 = *(const short8*)(Vc + dd*128 + (((4 + l4) ^ (dd & 7)) << 4));
            oA[dg] = __builtin_amdgcn_mfma_f32_16x16x32_bf16(v0, pf00, oA[dg], 0,0,0);
            oA[dg] = __builtin_amdgcn_mfma_f32_16x16x32_bf16(v1, pf01, oA[dg], 0,0,0);
            oB[dg] = __builtin_amdgcn_mfma_f32_16x16x32_bf16(v0, pf10, oB[dg], 0,0,0);
            oB[dg] = __builtin_amdgcn_mfma_f32_16x16x32_bf16(v1, pf11, oB[dg], 0,0,0);
        }
        __builtin_amdgcn_s_setprio(0);
    }

    // ---- epilogue: reduce l, subtract exact pad count (63), store ----
    const float liA = 1.f / (red_sum(lA) - 63.f);
    const float liB = 1.f / (red_sum(lB) - 63.f);
    const int b = bh / NH, h = bh % NH;
    const int qA = q0 + w*32 + l15;
    const int qB = qA + 16;
    if (qA < NTOK) {
        unsigned short* p = Obf + ((size_t)b*NTOK + qA)*DIM + h*HD + l4*4;
#pragma unroll
        for (int dg = 0; dg < 4; ++dg) {
            uint2 pk;
            pk.x = f2bf(oA[dg][0]*liA) | (f2bf(oA[dg][1]*liA) << 16);
            pk.y = f2bf(oA[dg][2]*liA) | (f2bf(oA[dg][3]*liA) << 16);
            *(uint2*)(p + dg*16) = pk;
        }
    }
    if (qB < NTOK) {
        unsigned short* p = Obf + ((size_t)b*NTOK + qB)*DIM + h*HD + l4*4;
#pragma unroll
        for (int dg = 0; dg < 4; ++dg) {
            uint2 pk;
            pk.x = f2bf(oB[dg][0]*liB) | (f2bf(oB[dg][1]*liB) << 16);
            pk.y = f2bf(oB[dg][2]*liB) | (f2bf(oB[dg][3]*liB) << 16);
            *(uint2*)(p + dg*16) = pk;
        }
    }
}

// ------------------------------------------------------------------
// Kernel 3: proj GEMM (feat=768, tok=16400), fp32 out + bias.
// grid (6, 129), block 256.
// ------------------------------------------------------------------
__global__ __launch_bounds__(256) void proj_gemm_kernel(
    const unsigned short* __restrict__ Wpb, const unsigned short* __restrict__ Obf,
    const float* __restrict__ bp, float* __restrict__ out)
{
    __shared__ __align__(16) short Ws[128*64];
    __shared__ __align__(16) short Xs[128*64];
    f32x4 acc[4][4] = {};
    const int tid = threadIdx.x;
    const int D0 = blockIdx.x * 128;
    const int T0 = blockIdx.y * 128;
    gemm_core(Wpb, Obf, D0, T0, MTOT - 1, Ws, Xs, acc, tid);

    const int lane = tid & 63;
    const int wu = tid >> 6, wr = wu >> 1, wc = wu & 1;
    const int l4 = lane >> 4, l15 = lane & 15;

    unsigned mArr[4];
    bool vArr[4];
#pragma unroll
    for (int fn = 0; fn < 4; ++fn) {
        unsigned m = T0 + wc*64 + fn*16 + l15;
        mArr[fn] = m;
        vArr[fn] = m < MTOT;
    }
#pragma unroll
    for (int fm = 0; fm < 4; ++fm) {
        const int nG = D0 + wr*64 + fm*16 + l4*4;
        const float4 bias = *(const float4*)&bp[nG];
#pragma unroll
        for (int fn = 0; fn < 4; ++fn) {
            if (!vArr[fn]) continue;
            f32x4 a = acc[fm][fn];
            float4 v = make_float4(a[0]+bias.x, a[1]+bias.y, a[2]+bias.z, a[3]+bias.w);
            *(float4*)&out[(size_t)mArr[fn]*DIM + nG] = v;
        }
    }
}

extern "C" void kernel_launch(void* const* d_in, const int* in_sizes, int n_in,
                              void* d_out, int out_size, void* d_ws, size_t ws_size,
                              hipStream_t stream)
{
    const float* x     = (const float*)d_in[0];
    const float* Wqkv  = (const float*)d_in[1];
    const float* Wp    = (const float*)d_in[2];
    const float* bp    = (const float*)d_in[3];
    const float* freqs = (const float*)d_in[4];
    float* out = (float*)d_out;

    const size_t SZP = (size_t)BATCH * NH * NTOKP * HD;  // 13,369,344
    const size_t SZ  = (size_t)BATCH * NH * NTOK  * HD;  // 12,595,200
    unsigned short* Qb  = (unsigned short*)d_ws;
    unsigned short* Kb  = Qb + SZP;
    unsigned short* Vb  = Kb + SZP;
    unsigned short* Obf = Vb + SZP;
    unsigned short* xb  = Obf + SZ;
    unsigned short* Wqb = xb + SZ;
    unsigned short* Wpb = Wqb + (size_t)QKVD * DIM;
    float2*         tab = (float2*)(Wpb + (size_t)DIM * DIM);

    cvt_bf16_kernel<<<2048, 256, 0, stream>>>(x, Wqkv, Wp, xb, Wqb, Wpb);
    rope_tab_kernel<<<1536, 256, 0, stream>>>(freqs, tab);
    pad_zero_kernel<<<1134, 256, 0, stream>>>(Qb, Kb, Vb);
    qkv_gemm_kernel<<<dim3(QKVD/128, (MTOT + 127)/128), 256, 0, stream>>>(
        Wqb, xb, tab, Qb, Kb, Vb);
    attn_mfma_kernel<<<1728, 256, 0, stream>>>(Qb, Kb, Vb, Obf);
    proj_gemm_kernel<<<dim3(DIM/128, (MTOT + 127)/128), 256, 0, stream>>>(
        Wpb, Obf, bp, out);
}

// Round 10
// 271.088 us; speedup vs baseline: 1.0958x; 1.0958x over previous
//
#include <hip/hip_runtime.h>
#include <math.h>

#define DIM     768
#define NH      12
#define HD      64
#define NTOK    1025
#define BATCH   16
#define MTOT    (BATCH * NTOK)        // 16400
#define QKVD    (3 * DIM)             // 2304

typedef short  short8  __attribute__((ext_vector_type(8)));
typedef short  short4v __attribute__((ext_vector_type(4)));
typedef float  f32x4   __attribute__((ext_vector_type(4)));

typedef const __attribute__((address_space(1))) void gvoid_t;
typedef __attribute__((address_space(3)))       void lvoid_t;
typedef __attribute__((address_space(3)))       char lchar_t;
#define GLD16(gsrc, ldst) __builtin_amdgcn_global_load_lds( \
    (gvoid_t*)(gsrc), (lvoid_t*)(ldst), 16, 0, 0)

static __device__ __forceinline__ unsigned int f2bf(float f) {
    unsigned int u = __float_as_uint(f);
    u += 0x7FFFu + ((u >> 16) & 1u);      // RNE
    return u >> 16;
}

static __device__ __forceinline__ float red_sum(float x) {
    x += __shfl_xor(x, 16);
    x += __shfl_xor(x, 32);
    return x;
}

// ------------------------------------------------------------------
// Kernel 0: fp32 -> bf16 conversion of x, W_qkv, W_proj
// ------------------------------------------------------------------
__device__ __forceinline__ void cvt8(const float* __restrict__ src,
                                     unsigned short* __restrict__ dst, int i) {
    float4 a = *(const float4*)(src + (size_t)i*8);
    float4 b = *(const float4*)(src + (size_t)i*8 + 4);
    uint4 pk;
    pk.x = f2bf(a.x) | (f2bf(a.y) << 16);
    pk.y = f2bf(a.z) | (f2bf(a.w) << 16);
    pk.z = f2bf(b.x) | (f2bf(b.y) << 16);
    pk.w = f2bf(b.z) | (f2bf(b.w) << 16);
    *(uint4*)(dst + (size_t)i*8) = pk;
}

__global__ __launch_bounds__(256) void cvt_bf16_kernel(
    const float* __restrict__ x, const float* __restrict__ Wq,
    const float* __restrict__ Wp,
    unsigned short* __restrict__ xb, unsigned short* __restrict__ Wqb,
    unsigned short* __restrict__ Wpb)
{
    const int stride = gridDim.x * blockDim.x;
    const int tid = blockIdx.x * blockDim.x + threadIdx.x;
    for (int i = tid; i < MTOT*DIM/8;  i += stride) cvt8(x,  xb,  i);
    for (int i = tid; i < QKVD*DIM/8;  i += stride) cvt8(Wq, Wqb, i);
    for (int i = tid; i < DIM*DIM/8;   i += stride) cvt8(Wp, Wpb, i);
}

// ------------------------------------------------------------------
// Kernel 0b: RoPE cos/sin table  [h][n1][pair] float2, 393216 entries
// ------------------------------------------------------------------
__global__ __launch_bounds__(256) void rope_tab_kernel(
    const float* __restrict__ freqs, float2* __restrict__ tab)
{
    const int gid = blockIdx.x * 256 + threadIdx.x;     // < 393216
    const int p  = gid & 31;
    const int n1 = (gid >> 5) & 1023;
    const int h  = gid >> 15;
    const float tx = (float)(n1 & 31), ty = (float)(n1 >> 5);
    const float ang = tx * freqs[h*32 + p] + ty * freqs[384 + h*32 + p];
    float s, c;
    sincosf(ang, &s, &c);
    tab[gid] = make_float2(c, s);
}

// ------------------------------------------------------------------
// Shared bf16 MFMA GEMM core: C[feat][tok] = W[feat][k] * X[tok][k]^T
// K=768, tile 128x128, BK=64, 256 threads (4 waves 2x2, each 64x64).
// ------------------------------------------------------------------
__device__ __forceinline__ void gemm_core(
    const unsigned short* __restrict__ Wb,
    const unsigned short* __restrict__ Xb,
    int D0, int T0, int maxXrow,
    short* Ws, short* Xs, f32x4 acc[4][4], int tid)
{
    const int lane = tid & 63;
    const int wu   = __builtin_amdgcn_readfirstlane(tid >> 6);
    const int wr   = wu >> 1, wc = wu & 1;
    const int l4   = lane >> 4, l15 = lane & 15;

    const int srow = lane >> 3;
    const int schk = (lane & 7) ^ srow;
    const unsigned short* wsrc[4];
    const unsigned short* xsrc[4];
#pragma unroll
    for (int i = 0; i < 4; ++i) {
        int r = wu*32 + i*8 + srow;
        wsrc[i] = Wb + (size_t)(D0 + r) * DIM + schk*8;
        int xr = T0 + r; if (xr > maxXrow) xr = maxXrow;
        xsrc[i] = Xb + (size_t)xr * DIM + schk*8;
    }

    for (int kt = 0; kt < DIM/64; ++kt) {
        __syncthreads();
#pragma unroll
        for (int i = 0; i < 4; ++i) {
            GLD16(wsrc[i] + kt*64, &Ws[(wu*4 + i) * 512]);
            GLD16(xsrc[i] + kt*64, &Xs[(wu*4 + i) * 512]);
        }
        __syncthreads();

        short8 wf[4][2], xf[4][2];
#pragma unroll
        for (int f = 0; f < 4; ++f) {
            const int rw = wr*64 + f*16 + l15;
            const int rx = wc*64 + f*16 + l15;
#pragma unroll
            for (int kf = 0; kf < 2; ++kf) {
                wf[f][kf] = *(const short8*)&Ws[rw*64 + (((kf*4 + l4) ^ (rw & 7)) << 3)];
                xf[f][kf] = *(const short8*)&Xs[rx*64 + (((kf*4 + l4) ^ (rx & 7)) << 3)];
            }
        }
        __builtin_amdgcn_s_setprio(1);
#pragma unroll
        for (int kf = 0; kf < 2; ++kf)
#pragma unroll
            for (int fm = 0; fm < 4; ++fm)
#pragma unroll
                for (int fn = 0; fn < 4; ++fn)
                    acc[fm][fn] = __builtin_amdgcn_mfma_f32_16x16x32_bf16(
                        wf[fm][kf], xf[fn][kf], acc[fm][fn], 0, 0, 0);
        __builtin_amdgcn_s_setprio(0);
    }
}

// ------------------------------------------------------------------
// Kernel 1: QKV GEMM + fused RoPE (table), bf16 out to Q/K/V (B,H,N,64)
// Q pre-scaled by scale*log2(e). grid (18, 129), block 256.
// ------------------------------------------------------------------
__global__ __launch_bounds__(256) void qkv_gemm_kernel(
    const unsigned short* __restrict__ Wqb, const unsigned short* __restrict__ xb,
    const float2* __restrict__ tab,
    unsigned short* __restrict__ Qb, unsigned short* __restrict__ Kb,
    unsigned short* __restrict__ Vb)
{
    __shared__ __align__(16) short Ws[128*64];
    __shared__ __align__(16) short Xs[128*64];
    f32x4 acc[4][4] = {};
    const int tid = threadIdx.x;
    const int D0 = blockIdx.x * 128;
    const int T0 = blockIdx.y * 128;
    gemm_core(Wqb, xb, D0, T0, MTOT - 1, Ws, Xs, acc, tid);

    const int lane = tid & 63;
    const int wu = tid >> 6, wr = wu >> 1, wc = wu & 1;
    const int l4 = lane >> 4, l15 = lane & 15;
    const int which = D0 / DIM;
    unsigned short* dst = (which == 0) ? Qb : (which == 1) ? Kb : Vb;
    const float qs = (which == 0) ? 0.125f * 1.44269504089f : 1.f;

    unsigned bArr[4], nArr[4];
    bool vArr[4];
#pragma unroll
    for (int fn = 0; fn < 4; ++fn) {
        unsigned m = T0 + wc*64 + fn*16 + l15;
        vArr[fn] = m < MTOT;
        bArr[fn] = m / NTOK;
        nArr[fn] = m - bArr[fn]*NTOK;
    }
#pragma unroll
    for (int fm = 0; fm < 4; ++fm) {
        const int hcol = (D0 % DIM) + wr*64 + fm*16 + l4*4;
        const int h = hcol >> 6, dd = hcol & 63;
        const int p0 = dd >> 1;                    // even
#pragma unroll
        for (int fn = 0; fn < 4; ++fn) {
            if (!vArr[fn]) continue;
            f32x4 a = acc[fm][fn];
            const int n = nArr[fn];
            if (which < 2) {                       // RoPE on Q,K (not CLS)
                int n1 = n > 0 ? n - 1 : 0;
                float4 cs = *(const float4*)&tab[(size_t)(h*1024 + n1)*32 + p0];
                if (n == 0) cs = make_float4(1.f, 0.f, 1.f, 0.f);
                float e0 = a[0], od0 = a[1], e1 = a[2], od1 = a[3];
                a[0] = e0*cs.x - od0*cs.y;  a[1] = e0*cs.y + od0*cs.x;
                a[2] = e1*cs.z - od1*cs.w;  a[3] = e1*cs.w + od1*cs.z;
            }
            uint2 pk;
            pk.x = f2bf(a[0]*qs) | (f2bf(a[1]*qs) << 16);
            pk.y = f2bf(a[2]*qs) | (f2bf(a[3]*qs) << 16);
            *(uint2*)&dst[((size_t)(bArr[fn]*NH + h)*NTOK + n)*HD + dd] = pk;
        }
    }
}

// ------------------------------------------------------------------
// Kernel 2: bf16 MFMA flash attention (R8 base), V path via
// global_load_lds into [T][D][4][16] subtiles + ds_read_b64_tr_b16.
// O^T, no max tracking, dbuf K/V, one barrier/tile, grid 1728.
// ------------------------------------------------------------------
__global__ __launch_bounds__(256) void attn_mfma_kernel(
    const unsigned short* __restrict__ Qb,
    const unsigned short* __restrict__ Kb,
    const unsigned short* __restrict__ Vb,
    unsigned short* __restrict__ Obf)
{
    __shared__ __align__(16) char KsR[2][8192];   // [tok][64d], chunk^(tok&7)
    __shared__ __align__(16) char VtR[2][8192];   // [T=16][D=4][t=4][dd=16] bf16
    __shared__ __align__(16) char PsR[4][4096];   // per wave [32q][64tok], swz

    const int tid  = threadIdx.x;
    const int lane = tid & 63;
    const int w    = __builtin_amdgcn_readfirstlane(tid >> 6);
    const int l4   = lane >> 4, l15 = lane & 15, l7 = lane & 7;

    const int d    = blockIdx.x;
    const int xcd  = d & 7;
    const int s    = d >> 3;                 // 0..215
    const int bh   = xcd * 24 + s / 9;
    const int q0   = (s % 9) * 128;
    const size_t base = (size_t)bh * NTOK * HD;

    // Q frags (pre-scaled by scale*log2e)
    short8 qf[2][2];
#pragma unroll
    for (int qg = 0; qg < 2; ++qg) {
        int qr = q0 + w*32 + qg*16 + l15;
        int qrc = qr < NTOK ? qr : NTOK - 1;
        qf[qg][0] = *(const short8*)(Qb + base + (size_t)qrc*HD + l4*8);
        qf[qg][1] = *(const short8*)(Qb + base + (size_t)qrc*HD + 32 + l4*8);
    }

    float lA = 0.f, lB = 0.f;
    f32x4 oA[4] = {}, oB[4] = {};          // O^T: row=d (l4,r), col=q (l15)

    // K staging params (as R8)
    const int ktokb = tid >> 3;                  // 0..31
    const int kchk  = tid & 7;
    // V staging params: chunk c -> (T,D,t,h8) subtile source
    const int c0 = tid, c1 = tid + 256;
    const int vt0 = ((c0 >> 5) << 2) | ((c0 >> 1) & 3);   // tile-local tok
    const int vt1 = ((c1 >> 5) << 2) | ((c1 >> 1) & 3);
    const int vo0 = (((c0 >> 3) & 3) << 4) | ((c0 & 1) << 3); // d offset
    const int vo1 = (((c1 >> 3) & 3) << 4) | ((c1 & 1) << 3);
    char* Pw = &PsR[w][0];

    // ---- prologue: stage tile 0 (K + V, all GLD) ----
#pragma unroll
    for (int i = 0; i < 2; ++i) {
        int tok = ktokb + i*32;
        int sc = kchk ^ (tok & 7);
        GLD16(Kb + base + (size_t)tok*HD + sc*8, &KsR[0][w*1024 + i*4096]);
    }
    GLD16(Vb + base + (size_t)vt0*HD + vo0, &VtR[0][w*1024]);
    GLD16(Vb + base + (size_t)vt1*HD + vo1, &VtR[0][4096 + w*1024]);

    for (int kt = 0; kt < 17; ++kt) {
        const int buf = kt & 1;
        __syncthreads();   // tile kt staged & visible (drains all GLDs)

        if (kt < 16) {
            const int nb = buf ^ 1;
#pragma unroll
            for (int i = 0; i < 2; ++i) {
                int tok = ktokb + i*32;
                int gk = (kt+1)*64 + tok; if (gk > NTOK-1) gk = NTOK-1;
                int sc = kchk ^ (tok & 7);
                GLD16(Kb + base + (size_t)gk*HD + sc*8, &KsR[nb][w*1024 + i*4096]);
            }
            int g0 = (kt+1)*64 + vt0; if (g0 > NTOK-1) g0 = NTOK-1;
            int g1 = (kt+1)*64 + vt1; if (g1 > NTOK-1) g1 = NTOK-1;
            GLD16(Vb + base + (size_t)g0*HD + vo0, &VtR[nb][w*1024]);
            GLD16(Vb + base + (size_t)g1*HD + vo1, &VtR[nb][4096 + w*1024]);
        }

        // ---- S^T = K @ Q^T  (lane: q = l15, tok = tg*16 + l4*4 + r) ----
        f32x4 sA[4] = {}, sB[4] = {};
        __builtin_amdgcn_s_setprio(1);
#pragma unroll
        for (int tg = 0; tg < 4; ++tg) {
            const int row = tg*16 + l15;
            short8 ka0 = *(const short8*)(&KsR[buf][0] + row*128 + ((l4 ^ l7) << 4));
            short8 ka1 = *(const short8*)(&KsR[buf][0] + row*128 + (((4 + l4) ^ l7) << 4));
            sA[tg] = __builtin_amdgcn_mfma_f32_16x16x32_bf16(ka0, qf[0][0], sA[tg], 0,0,0);
            sA[tg] = __builtin_amdgcn_mfma_f32_16x16x32_bf16(ka1, qf[0][1], sA[tg], 0,0,0);
            sB[tg] = __builtin_amdgcn_mfma_f32_16x16x32_bf16(ka0, qf[1][0], sB[tg], 0,0,0);
            sB[tg] = __builtin_amdgcn_mfma_f32_16x16x32_bf16(ka1, qf[1][1], sB[tg], 0,0,0);
        }
        __builtin_amdgcn_s_setprio(0);

        // ---- p = exp2(s); mask only last tile (p=0 protects clamped V) ----
        float pA[16], pB[16];
        if (kt == 16) {
#pragma unroll
            for (int tg = 0; tg < 4; ++tg)
#pragma unroll
                for (int r = 0; r < 4; ++r) {
                    int tok = 1024 + tg*16 + l4*4 + r;
                    float sa = (tok > 1024) ? -3e38f : sA[tg][r];
                    float sb = (tok > 1024) ? -3e38f : sB[tg][r];
                    pA[tg*4+r] = __builtin_exp2f(sa);
                    pB[tg*4+r] = __builtin_exp2f(sb);
                }
        } else {
#pragma unroll
            for (int tg = 0; tg < 4; ++tg)
#pragma unroll
                for (int r = 0; r < 4; ++r) {
                    pA[tg*4+r] = __builtin_exp2f(sA[tg][r]);
                    pB[tg*4+r] = __builtin_exp2f(sB[tg][r]);
                }
        }
        float psA = 0.f, psB = 0.f;
#pragma unroll
        for (int i = 0; i < 16; ++i) { psA += pA[i]; psB += pB[i]; }
        lA += psA;
        lB += psB;

        // ---- P -> LDS (packed bf16 pairs, b64 writes, swizzled) ----
#pragma unroll
        for (int tg = 0; tg < 4; ++tg) {
            unsigned k0a, k1a, k0b, k1b;
            asm volatile("v_cvt_pk_bf16_f32 %0, %1, %2" : "=v"(k0a) : "v"(pA[tg*4+0]), "v"(pA[tg*4+1]));
            asm volatile("v_cvt_pk_bf16_f32 %0, %1, %2" : "=v"(k1a) : "v"(pA[tg*4+2]), "v"(pA[tg*4+3]));
            asm volatile("v_cvt_pk_bf16_f32 %0, %1, %2" : "=v"(k0b) : "v"(pB[tg*4+0]), "v"(pB[tg*4+1]));
            asm volatile("v_cvt_pk_bf16_f32 %0, %1, %2" : "=v"(k1b) : "v"(pB[tg*4+2]), "v"(pB[tg*4+3]));
            const int chk = (((tg*2 + (l4 >> 1)) ^ l7) << 4) + (l4 & 1)*8;
            *(uint2*)(Pw + l15*128      + chk) = make_uint2(k0a, k1a);
            *(uint2*)(Pw + (16+l15)*128 + chk) = make_uint2(k0b, k1b);
        }
        __builtin_amdgcn_wave_barrier();

        const short8 pf00 = *(const short8*)(Pw + l15*128      + ((l4 ^ l7) << 4));
        const short8 pf01 = *(const short8*)(Pw + l15*128      + (((4+l4) ^ l7) << 4));
        const short8 pf10 = *(const short8*)(Pw + (16+l15)*128 + ((l4 ^ l7) << 4));
        const short8 pf11 = *(const short8*)(Pw + (16+l15)*128 + (((4+l4) ^ l7) << 4));

        // ---- O^T += V^T @ P via hardware transpose reads ----
        // lane addr: window(l4 group) + col(l15); dg,c,half in offsets.
        const unsigned trb = (unsigned)(unsigned long long)
            (lchar_t*)(&VtR[buf][0] + (l4 << 10) + (l15 << 3));
        short4v r0a, r0b, r1a, r1b, r2a, r2b, r3a, r3b;

        // toks 0..31 (half 0): offset = dg*128 + c*512
        asm volatile(
            "ds_read_b64_tr_b16 %0, %8 offset:0\n\t"
            "ds_read_b64_tr_b16 %1, %8 offset:512\n\t"
            "ds_read_b64_tr_b16 %2, %8 offset:128\n\t"
            "ds_read_b64_tr_b16 %3, %8 offset:640\n\t"
            "ds_read_b64_tr_b16 %4, %8 offset:256\n\t"
            "ds_read_b64_tr_b16 %5, %8 offset:768\n\t"
            "ds_read_b64_tr_b16 %6, %8 offset:384\n\t"
            "ds_read_b64_tr_b16 %7, %8 offset:896\n\t"
            "s_waitcnt lgkmcnt(0)"
            : "=&v"(r0a), "=&v"(r0b), "=&v"(r1a), "=&v"(r1b),
              "=&v"(r2a), "=&v"(r2b), "=&v"(r3a), "=&v"(r3b)
            : "v"(trb) : "memory");
        __builtin_amdgcn_sched_barrier(0);
        {
            short8 v0 = __builtin_shufflevector(r0a, r0b, 0,1,2,3,4,5,6,7);
            short8 v1 = __builtin_shufflevector(r1a, r1b, 0,1,2,3,4,5,6,7);
            short8 v2 = __builtin_shufflevector(r2a, r2b, 0,1,2,3,4,5,6,7);
            short8 v3 = __builtin_shufflevector(r3a, r3b, 0,1,2,3,4,5,6,7);
            __builtin_amdgcn_s_setprio(1);
            oA[0] = __builtin_amdgcn_mfma_f32_16x16x32_bf16(v0, pf00, oA[0], 0,0,0);
            oB[0] = __builtin_amdgcn_mfma_f32_16x16x32_bf16(v0, pf10, oB[0], 0,0,0);
            oA[1] = __builtin_amdgcn_mfma_f32_16x16x32_bf16(v1, pf00, oA[1], 0,0,0);
            oB[1] = __builtin_amdgcn_mfma_f32_16x16x32_bf16(v1, pf10, oB[1], 0,0,0);
            oA[2] = __builtin_amdgcn_mfma_f32_16x16x32_bf16(v2, pf00, oA[2], 0,0,0);
            oB[2] = __builtin_amdgcn_mfma_f32_16x16x32_bf16(v2, pf10, oB[2], 0,0,0);
            oA[3] = __builtin_amdgcn_mfma_f32_16x16x32_bf16(v3, pf00, oA[3], 0,0,0);
            oB[3] = __builtin_amdgcn_mfma_f32_16x16x32_bf16(v3, pf10, oB[3], 0,0,0);
            __builtin_amdgcn_s_setprio(0);
        }
        // toks 32..63 (half 1): offsets + 4096
        asm volatile(
            "ds_read_b64_tr_b16 %0, %8 offset:4096\n\t"
            "ds_read_b64_tr_b16 %1, %8 offset:4608\n\t"
            "ds_read_b64_tr_b16 %2, %8 offset:4224\n\t"
            "ds_read_b64_tr_b16 %3, %8 offset:4736\n\t"
            "ds_read_b64_tr_b16 %4, %8 offset:4352\n\t"
            "ds_read_b64_tr_b16 %5, %8 offset:4864\n\t"
            "ds_read_b64_tr_b16 %6, %8 offset:4480\n\t"
            "ds_read_b64_tr_b16 %7, %8 offset:4992\n\t"
            "s_waitcnt lgkmcnt(0)"
            : "=&v"(r0a), "=&v"(r0b), "=&v"(r1a), "=&v"(r1b),
              "=&v"(r2a), "=&v"(r2b), "=&v"(r3a), "=&v"(r3b)
            : "v"(trb) : "memory");
        __builtin_amdgcn_sched_barrier(0);
        {
            short8 v0 = __builtin_shufflevector(r0a, r0b, 0,1,2,3,4,5,6,7);
            short8 v1 = __builtin_shufflevector(r1a, r1b, 0,1,2,3,4,5,6,7);
            short8 v2 = __builtin_shufflevector(r2a, r2b, 0,1,2,3,4,5,6,7);
            short8 v3 = __builtin_shufflevector(r3a, r3b, 0,1,2,3,4,5,6,7);
            __builtin_amdgcn_s_setprio(1);
            oA[0] = __builtin_amdgcn_mfma_f32_16x16x32_bf16(v0, pf01, oA[0], 0,0,0);
            oB[0] = __builtin_amdgcn_mfma_f32_16x16x32_bf16(v0, pf11, oB[0], 0,0,0);
            oA[1] = __builtin_amdgcn_mfma_f32_16x16x32_bf16(v1, pf01, oA[1], 0,0,0);
            oB[1] = __builtin_amdgcn_mfma_f32_16x16x32_bf16(v1, pf11, oB[1], 0,0,0);
            oA[2] = __builtin_amdgcn_mfma_f32_16x16x32_bf16(v2, pf01, oA[2], 0,0,0);
            oB[2] = __builtin_amdgcn_mfma_f32_16x16x32_bf16(v2, pf11, oB[2], 0,0,0);
            oA[3] = __builtin_amdgcn_mfma_f32_16x16x32_bf16(v3, pf01, oA[3], 0,0,0);
            oB[3] = __builtin_amdgcn_mfma_f32_16x16x32_bf16(v3, pf11, oB[3], 0,0,0);
            __builtin_amdgcn_s_setprio(0);
        }
    }

    // ---- epilogue: single cross-lane reduce of l, then store O^T ----
    const float liA = 1.f / red_sum(lA);
    const float liB = 1.f / red_sum(lB);
    const int b = bh / NH, h = bh % NH;
    const int qA = q0 + w*32 + l15;
    const int qB = qA + 16;
    if (qA < NTOK) {
        unsigned short* p = Obf + ((size_t)b*NTOK + qA)*DIM + h*HD + l4*4;
#pragma unroll
        for (int dg = 0; dg < 4; ++dg) {
            uint2 pk;
            pk.x = f2bf(oA[dg][0]*liA) | (f2bf(oA[dg][1]*liA) << 16);
            pk.y = f2bf(oA[dg][2]*liA) | (f2bf(oA[dg][3]*liA) << 16);
            *(uint2*)(p + dg*16) = pk;
        }
    }
    if (qB < NTOK) {
        unsigned short* p = Obf + ((size_t)b*NTOK + qB)*DIM + h*HD + l4*4;
#pragma unroll
        for (int dg = 0; dg < 4; ++dg) {
            uint2 pk;
            pk.x = f2bf(oB[dg][0]*liB) | (f2bf(oB[dg][1]*liB) << 16);
            pk.y = f2bf(oB[dg][2]*liB) | (f2bf(oB[dg][3]*liB) << 16);
            *(uint2*)(p + dg*16) = pk;
        }
    }
}

// ------------------------------------------------------------------
// Kernel 3: proj GEMM (feat=768, tok=16400), fp32 out + bias.
// grid (6, 129), block 256.
// ------------------------------------------------------------------
__global__ __launch_bounds__(256) void proj_gemm_kernel(
    const unsigned short* __restrict__ Wpb, const unsigned short* __restrict__ Obf,
    const float* __restrict__ bp, float* __restrict__ out)
{
    __shared__ __align__(16) short Ws[128*64];
    __shared__ __align__(16) short Xs[128*64];
    f32x4 acc[4][4] = {};
    const int tid = threadIdx.x;
    const int D0 = blockIdx.x * 128;
    const int T0 = blockIdx.y * 128;
    gemm_core(Wpb, Obf, D0, T0, MTOT - 1, Ws, Xs, acc, tid);

    const int lane = tid & 63;
    const int wu = tid >> 6, wr = wu >> 1, wc = wu & 1;
    const int l4 = lane >> 4, l15 = lane & 15;

    unsigned mArr[4];
    bool vArr[4];
#pragma unroll
    for (int fn = 0; fn < 4; ++fn) {
        unsigned m = T0 + wc*64 + fn*16 + l15;
        mArr[fn] = m;
        vArr[fn] = m < MTOT;
    }
#pragma unroll
    for (int fm = 0; fm < 4; ++fm) {
        const int nG = D0 + wr*64 + fm*16 + l4*4;
        const float4 bias = *(const float4*)&bp[nG];
#pragma unroll
        for (int fn = 0; fn < 4; ++fn) {
            if (!vArr[fn]) continue;
            f32x4 a = acc[fm][fn];
            float4 v = make_float4(a[0]+bias.x, a[1]+bias.y, a[2]+bias.z, a[3]+bias.w);
            *(float4*)&out[(size_t)mArr[fn]*DIM + nG] = v;
        }
    }
}

extern "C" void kernel_launch(void* const* d_in, const int* in_sizes, int n_in,
                              void* d_out, int out_size, void* d_ws, size_t ws_size,
                              hipStream_t stream)
{
    const float* x     = (const float*)d_in[0];
    const float* Wqkv  = (const float*)d_in[1];
    const float* Wp    = (const float*)d_in[2];
    const float* bp    = (const float*)d_in[3];
    const float* freqs = (const float*)d_in[4];
    float* out = (float*)d_out;

    const size_t SZ = (size_t)BATCH * NH * NTOK * HD;  // 12,595,200
    unsigned short* Qb  = (unsigned short*)d_ws;
    unsigned short* Kb  = Qb + SZ;
    unsigned short* Vb  = Kb + SZ;
    unsigned short* Obf = Vb + SZ;
    unsigned short* xb  = Obf + SZ;
    unsigned short* Wqb = xb + SZ;
    unsigned short* Wpb = Wqb + (size_t)QKVD * DIM;
    float2*         tab = (float2*)(Wpb + (size_t)DIM * DIM);

    cvt_bf16_kernel<<<2048, 256, 0, stream>>>(x, Wqkv, Wp, xb, Wqb, Wpb);
    rope_tab_kernel<<<1536, 256, 0, stream>>>(freqs, tab);
    qkv_gemm_kernel<<<dim3(QKVD/128, (MTOT + 127)/128), 256, 0, stream>>>(
        Wqb, xb, tab, Qb, Kb, Vb);
    attn_mfma_kernel<<<1728, 256, 0, stream>>>(Qb, Kb, Vb, Obf);
    proj_gemm_kernel<<<dim3(DIM/128, (MTOT + 127)/128), 256, 0, stream>>>(
        Wpb, Obf, bp, out);
}

// Round 11
// 268.307 us; speedup vs baseline: 1.1072x; 1.0104x over previous
//
#include <hip/hip_runtime.h>
#include <math.h>

#define DIM     768
#define NH      12
#define HD      64
#define NTOK    1025
#define BATCH   16
#define MTOT    (BATCH * NTOK)        // 16400
#define QKVD    (3 * DIM)             // 2304

typedef short  short8  __attribute__((ext_vector_type(8)));
typedef short  short4v __attribute__((ext_vector_type(4)));
typedef float  f32x4   __attribute__((ext_vector_type(4)));

typedef const __attribute__((address_space(1))) void gvoid_t;
typedef __attribute__((address_space(3)))       void lvoid_t;
typedef __attribute__((address_space(3)))       char lchar_t;
#define GLD16(gsrc, ldst) __builtin_amdgcn_global_load_lds( \
    (gvoid_t*)(gsrc), (lvoid_t*)(ldst), 16, 0, 0)

static __device__ __forceinline__ unsigned int f2bf(float f) {
    unsigned int u = __float_as_uint(f);
    u += 0x7FFFu + ((u >> 16) & 1u);      // RNE
    return u >> 16;
}

static __device__ __forceinline__ float red_sum(float x) {
    x += __shfl_xor(x, 16);
    x += __shfl_xor(x, 32);
    return x;
}

// ------------------------------------------------------------------
// Kernel 0: fp32 -> bf16 conversion of x, W_qkv, W_proj
// ------------------------------------------------------------------
__device__ __forceinline__ void cvt8(const float* __restrict__ src,
                                     unsigned short* __restrict__ dst, int i) {
    float4 a = *(const float4*)(src + (size_t)i*8);
    float4 b = *(const float4*)(src + (size_t)i*8 + 4);
    uint4 pk;
    pk.x = f2bf(a.x) | (f2bf(a.y) << 16);
    pk.y = f2bf(a.z) | (f2bf(a.w) << 16);
    pk.z = f2bf(b.x) | (f2bf(b.y) << 16);
    pk.w = f2bf(b.z) | (f2bf(b.w) << 16);
    *(uint4*)(dst + (size_t)i*8) = pk;
}

__global__ __launch_bounds__(256) void cvt_bf16_kernel(
    const float* __restrict__ x, const float* __restrict__ Wq,
    const float* __restrict__ Wp,
    unsigned short* __restrict__ xb, unsigned short* __restrict__ Wqb,
    unsigned short* __restrict__ Wpb)
{
    const int stride = gridDim.x * blockDim.x;
    const int tid = blockIdx.x * blockDim.x + threadIdx.x;
    for (int i = tid; i < MTOT*DIM/8;  i += stride) cvt8(x,  xb,  i);
    for (int i = tid; i < QKVD*DIM/8;  i += stride) cvt8(Wq, Wqb, i);
    for (int i = tid; i < DIM*DIM/8;   i += stride) cvt8(Wp, Wpb, i);
}

// ------------------------------------------------------------------
// Kernel 0b: RoPE cos/sin table  [h][n1][pair] float2, 393216 entries
// ------------------------------------------------------------------
__global__ __launch_bounds__(256) void rope_tab_kernel(
    const float* __restrict__ freqs, float2* __restrict__ tab)
{
    const int gid = blockIdx.x * 256 + threadIdx.x;     // < 393216
    const int p  = gid & 31;
    const int n1 = (gid >> 5) & 1023;
    const int h  = gid >> 15;
    const float tx = (float)(n1 & 31), ty = (float)(n1 >> 5);
    const float ang = tx * freqs[h*32 + p] + ty * freqs[384 + h*32 + p];
    float s, c;
    sincosf(ang, &s, &c);
    tab[gid] = make_float2(c, s);
}

// ------------------------------------------------------------------
// Shared bf16 MFMA GEMM core: C[feat][tok] = W[feat][k] * X[tok][k]^T
// K=768, tile 128x128, BK=64, 256 threads (4 waves 2x2, each 64x64).
// ------------------------------------------------------------------
__device__ __forceinline__ void gemm_core(
    const unsigned short* __restrict__ Wb,
    const unsigned short* __restrict__ Xb,
    int D0, int T0, int maxXrow,
    short* Ws, short* Xs, f32x4 acc[4][4], int tid)
{
    const int lane = tid & 63;
    const int wu   = __builtin_amdgcn_readfirstlane(tid >> 6);
    const int wr   = wu >> 1, wc = wu & 1;
    const int l4   = lane >> 4, l15 = lane & 15;

    const int srow = lane >> 3;
    const int schk = (lane & 7) ^ srow;
    const unsigned short* wsrc[4];
    const unsigned short* xsrc[4];
#pragma unroll
    for (int i = 0; i < 4; ++i) {
        int r = wu*32 + i*8 + srow;
        wsrc[i] = Wb + (size_t)(D0 + r) * DIM + schk*8;
        int xr = T0 + r; if (xr > maxXrow) xr = maxXrow;
        xsrc[i] = Xb + (size_t)xr * DIM + schk*8;
    }

    for (int kt = 0; kt < DIM/64; ++kt) {
        __syncthreads();
#pragma unroll
        for (int i = 0; i < 4; ++i) {
            GLD16(wsrc[i] + kt*64, &Ws[(wu*4 + i) * 512]);
            GLD16(xsrc[i] + kt*64, &Xs[(wu*4 + i) * 512]);
        }
        __syncthreads();

        short8 wf[4][2], xf[4][2];
#pragma unroll
        for (int f = 0; f < 4; ++f) {
            const int rw = wr*64 + f*16 + l15;
            const int rx = wc*64 + f*16 + l15;
#pragma unroll
            for (int kf = 0; kf < 2; ++kf) {
                wf[f][kf] = *(const short8*)&Ws[rw*64 + (((kf*4 + l4) ^ (rw & 7)) << 3)];
                xf[f][kf] = *(const short8*)&Xs[rx*64 + (((kf*4 + l4) ^ (rx & 7)) << 3)];
            }
        }
        __builtin_amdgcn_s_setprio(1);
#pragma unroll
        for (int kf = 0; kf < 2; ++kf)
#pragma unroll
            for (int fm = 0; fm < 4; ++fm)
#pragma unroll
                for (int fn = 0; fn < 4; ++fn)
                    acc[fm][fn] = __builtin_amdgcn_mfma_f32_16x16x32_bf16(
                        wf[fm][kf], xf[fn][kf], acc[fm][fn], 0, 0, 0);
        __builtin_amdgcn_s_setprio(0);
    }
}

// ------------------------------------------------------------------
// Kernel 1: QKV GEMM + fused RoPE (table), bf16 out to Q/K/V (B,H,N,64)
// Q pre-scaled by scale*log2(e). 1D grid 2322, XCD-chunked so all 18
// D0-blocks of one token panel land on one XCD (x-panel L2 reuse).
// ------------------------------------------------------------------
__global__ __launch_bounds__(256) void qkv_gemm_kernel(
    const unsigned short* __restrict__ Wqb, const unsigned short* __restrict__ xb,
    const float2* __restrict__ tab,
    unsigned short* __restrict__ Qb, unsigned short* __restrict__ Kb,
    unsigned short* __restrict__ Vb)
{
    __shared__ __align__(16) short Ws[128*64];
    __shared__ __align__(16) short Xs[128*64];
    f32x4 acc[4][4] = {};
    const int tid = threadIdx.x;

    // bijective XCD swizzle: 2322 = 18 D0 x 129 T0-groups
    const int dd0 = blockIdx.x;
    int xc, j;
    if (dd0 >= 2304) { xc = 0; j = 288 + (dd0 - 2304); }
    else             { xc = dd0 & 7; j = dd0 >> 3; }
    const int D0 = (j % 18) * 128;
    const int T0 = (xc + 8 * (j / 18)) * 128;

    gemm_core(Wqb, xb, D0, T0, MTOT - 1, Ws, Xs, acc, tid);

    const int lane = tid & 63;
    const int wu = tid >> 6, wr = wu >> 1, wc = wu & 1;
    const int l4 = lane >> 4, l15 = lane & 15;
    const int which = D0 / DIM;
    unsigned short* dst = (which == 0) ? Qb : (which == 1) ? Kb : Vb;
    const float qs = (which == 0) ? 0.125f * 1.44269504089f : 1.f;

    unsigned bArr[4], nArr[4];
    bool vArr[4];
#pragma unroll
    for (int fn = 0; fn < 4; ++fn) {
        unsigned m = T0 + wc*64 + fn*16 + l15;
        vArr[fn] = m < MTOT;
        bArr[fn] = m / NTOK;
        nArr[fn] = m - bArr[fn]*NTOK;
    }
#pragma unroll
    for (int fm = 0; fm < 4; ++fm) {
        const int hcol = (D0 % DIM) + wr*64 + fm*16 + l4*4;
        const int h = hcol >> 6, dd = hcol & 63;
        const int p0 = dd >> 1;                    // even
#pragma unroll
        for (int fn = 0; fn < 4; ++fn) {
            if (!vArr[fn]) continue;
            f32x4 a = acc[fm][fn];
            const int n = nArr[fn];
            if (which < 2) {                       // RoPE on Q,K (not CLS)
                int n1 = n > 0 ? n - 1 : 0;
                float4 cs = *(const float4*)&tab[(size_t)(h*1024 + n1)*32 + p0];
                if (n == 0) cs = make_float4(1.f, 0.f, 1.f, 0.f);
                float e0 = a[0], od0 = a[1], e1 = a[2], od1 = a[3];
                a[0] = e0*cs.x - od0*cs.y;  a[1] = e0*cs.y + od0*cs.x;
                a[2] = e1*cs.z - od1*cs.w;  a[3] = e1*cs.w + od1*cs.z;
            }
            uint2 pk;
            pk.x = f2bf(a[0]*qs) | (f2bf(a[1]*qs) << 16);
            pk.y = f2bf(a[2]*qs) | (f2bf(a[3]*qs) << 16);
            *(uint2*)&dst[((size_t)(bArr[fn]*NH + h)*NTOK + n)*HD + dd] = pk;
        }
    }
}

// ------------------------------------------------------------------
// Kernel 2: bf16 MFMA flash attention. V via GLD subtiles +
// ds_read_b64_tr_b16; P in per-wave [32q][32tok] half-buffers
// (LDS 40KB -> 4 blocks/CU). O^T, no max tracking, dbuf K/V,
// one block barrier/tile, grid 1728 XCD-chunked.
// ------------------------------------------------------------------
__global__ __launch_bounds__(256) void attn_mfma_kernel(
    const unsigned short* __restrict__ Qb,
    const unsigned short* __restrict__ Kb,
    const unsigned short* __restrict__ Vb,
    unsigned short* __restrict__ Obf)
{
    __shared__ __align__(16) char KsR[2][8192];   // [tok][64d], chunk^(tok&7)
    __shared__ __align__(16) char VtR[2][8192];   // [T=16][D=4][t=4][dd=16] bf16
    __shared__ __align__(16) char PsR[4][2048];   // per wave [32q][32tok], swz

    const int tid  = threadIdx.x;
    const int lane = tid & 63;
    const int w    = __builtin_amdgcn_readfirstlane(tid >> 6);
    const int l4   = lane >> 4, l15 = lane & 15, l7 = lane & 7;

    const int d    = blockIdx.x;
    const int xcd  = d & 7;
    const int s    = d >> 3;                 // 0..215
    const int bh   = xcd * 24 + s / 9;
    const int q0   = (s % 9) * 128;
    const size_t base = (size_t)bh * NTOK * HD;

    // Q frags (pre-scaled by scale*log2e)
    short8 qf[2][2];
#pragma unroll
    for (int qg = 0; qg < 2; ++qg) {
        int qr = q0 + w*32 + qg*16 + l15;
        int qrc = qr < NTOK ? qr : NTOK - 1;
        qf[qg][0] = *(const short8*)(Qb + base + (size_t)qrc*HD + l4*8);
        qf[qg][1] = *(const short8*)(Qb + base + (size_t)qrc*HD + 32 + l4*8);
    }

    float lA = 0.f, lB = 0.f;
    f32x4 oA[4] = {}, oB[4] = {};          // O^T: row=d (l4,r), col=q (l15)

    // K staging params
    const int ktokb = tid >> 3;                  // 0..31
    const int kchk  = tid & 7;
    // V staging params: chunk c -> (T,D,t,h8) subtile source
    const int c0 = tid, c1 = tid + 256;
    const int vt0 = ((c0 >> 5) << 2) | ((c0 >> 1) & 3);   // tile-local tok
    const int vt1 = ((c1 >> 5) << 2) | ((c1 >> 1) & 3);
    const int vo0 = (((c0 >> 3) & 3) << 4) | ((c0 & 1) << 3); // d offset
    const int vo1 = (((c1 >> 3) & 3) << 4) | ((c1 & 1) << 3);
    char* Pw = &PsR[w][0];
    const int pwoff = ((l4 & 1) << 3);           // byte within chunk
    const int prd   = (l4 ^ (l15 & 3)) << 4;     // read chunk (swizzled)

    // ---- prologue: stage tile 0 (K + V, all GLD) ----
#pragma unroll
    for (int i = 0; i < 2; ++i) {
        int tok = ktokb + i*32;
        int sc = kchk ^ (tok & 7);
        GLD16(Kb + base + (size_t)tok*HD + sc*8, &KsR[0][w*1024 + i*4096]);
    }
    GLD16(Vb + base + (size_t)vt0*HD + vo0, &VtR[0][w*1024]);
    GLD16(Vb + base + (size_t)vt1*HD + vo1, &VtR[0][4096 + w*1024]);

    for (int kt = 0; kt < 17; ++kt) {
        const int buf = kt & 1;
        __syncthreads();   // tile kt staged & visible (drains all GLDs)

        if (kt < 16) {
            const int nb = buf ^ 1;
#pragma unroll
            for (int i = 0; i < 2; ++i) {
                int tok = ktokb + i*32;
                int gk = (kt+1)*64 + tok; if (gk > NTOK-1) gk = NTOK-1;
                int sc = kchk ^ (tok & 7);
                GLD16(Kb + base + (size_t)gk*HD + sc*8, &KsR[nb][w*1024 + i*4096]);
            }
            int g0 = (kt+1)*64 + vt0; if (g0 > NTOK-1) g0 = NTOK-1;
            int g1 = (kt+1)*64 + vt1; if (g1 > NTOK-1) g1 = NTOK-1;
            GLD16(Vb + base + (size_t)g0*HD + vo0, &VtR[nb][w*1024]);
            GLD16(Vb + base + (size_t)g1*HD + vo1, &VtR[nb][4096 + w*1024]);
        }

        // ---- S^T = K @ Q^T  (lane: q = l15, tok = tg*16 + l4*4 + r) ----
        f32x4 sA[4] = {}, sB[4] = {};
        __builtin_amdgcn_s_setprio(1);
#pragma unroll
        for (int tg = 0; tg < 4; ++tg) {
            const int row = tg*16 + l15;
            short8 ka0 = *(const short8*)(&KsR[buf][0] + row*128 + ((l4 ^ l7) << 4));
            short8 ka1 = *(const short8*)(&KsR[buf][0] + row*128 + (((4 + l4) ^ l7) << 4));
            sA[tg] = __builtin_amdgcn_mfma_f32_16x16x32_bf16(ka0, qf[0][0], sA[tg], 0,0,0);
            sA[tg] = __builtin_amdgcn_mfma_f32_16x16x32_bf16(ka1, qf[0][1], sA[tg], 0,0,0);
            sB[tg] = __builtin_amdgcn_mfma_f32_16x16x32_bf16(ka0, qf[1][0], sB[tg], 0,0,0);
            sB[tg] = __builtin_amdgcn_mfma_f32_16x16x32_bf16(ka1, qf[1][1], sB[tg], 0,0,0);
        }
        __builtin_amdgcn_s_setprio(0);

        // ---- p = exp2(s); mask only last tile ----
        float pA[16], pB[16];
        if (kt == 16) {
#pragma unroll
            for (int tg = 0; tg < 4; ++tg)
#pragma unroll
                for (int r = 0; r < 4; ++r) {
                    int tok = 1024 + tg*16 + l4*4 + r;
                    float sa = (tok > 1024) ? -3e38f : sA[tg][r];
                    float sb = (tok > 1024) ? -3e38f : sB[tg][r];
                    pA[tg*4+r] = __builtin_exp2f(sa);
                    pB[tg*4+r] = __builtin_exp2f(sb);
                }
        } else {
#pragma unroll
            for (int tg = 0; tg < 4; ++tg)
#pragma unroll
                for (int r = 0; r < 4; ++r) {
                    pA[tg*4+r] = __builtin_exp2f(sA[tg][r]);
                    pB[tg*4+r] = __builtin_exp2f(sB[tg][r]);
                }
        }
        float psA = 0.f, psB = 0.f;
#pragma unroll
        for (int i = 0; i < 16; ++i) { psA += pA[i]; psB += pB[i]; }
        lA += psA;
        lB += psB;

        const unsigned trb = (unsigned)(unsigned long long)
            (lchar_t*)(&VtR[buf][0] + (l4 << 10) + (l15 << 3));
        short4v r0a, r0b, r1a, r1b, r2a, r2b, r3a, r3b;

        // ================= half 0: toks 0..31 =================
#pragma unroll
        for (int tgl = 0; tgl < 2; ++tgl) {
            const int tg = tgl;            // global tg = 0,1
            unsigned k0a, k1a, k0b, k1b;
            asm volatile("v_cvt_pk_bf16_f32 %0, %1, %2" : "=v"(k0a) : "v"(pA[tg*4+0]), "v"(pA[tg*4+1]));
            asm volatile("v_cvt_pk_bf16_f32 %0, %1, %2" : "=v"(k1a) : "v"(pA[tg*4+2]), "v"(pA[tg*4+3]));
            asm volatile("v_cvt_pk_bf16_f32 %0, %1, %2" : "=v"(k0b) : "v"(pB[tg*4+0]), "v"(pB[tg*4+1]));
            asm volatile("v_cvt_pk_bf16_f32 %0, %1, %2" : "=v"(k1b) : "v"(pB[tg*4+2]), "v"(pB[tg*4+3]));
            const int boff = ((((tgl << 1) | (l4 >> 1)) ^ (l15 & 3)) << 4) + pwoff;
            *(uint2*)(Pw + l15*64        + boff) = make_uint2(k0a, k1a);
            *(uint2*)(Pw + (16 + l15)*64 + boff) = make_uint2(k0b, k1b);
        }
        __builtin_amdgcn_wave_barrier();
        {
            const short8 pfA = *(const short8*)(Pw + l15*64        + prd);
            const short8 pfB = *(const short8*)(Pw + (16 + l15)*64 + prd);
            asm volatile(
                "ds_read_b64_tr_b16 %0, %8 offset:0\n\t"
                "ds_read_b64_tr_b16 %1, %8 offset:512\n\t"
                "ds_read_b64_tr_b16 %2, %8 offset:128\n\t"
                "ds_read_b64_tr_b16 %3, %8 offset:640\n\t"
                "ds_read_b64_tr_b16 %4, %8 offset:256\n\t"
                "ds_read_b64_tr_b16 %5, %8 offset:768\n\t"
                "ds_read_b64_tr_b16 %6, %8 offset:384\n\t"
                "ds_read_b64_tr_b16 %7, %8 offset:896\n\t"
                "s_waitcnt lgkmcnt(0)"
                : "=&v"(r0a), "=&v"(r0b), "=&v"(r1a), "=&v"(r1b),
                  "=&v"(r2a), "=&v"(r2b), "=&v"(r3a), "=&v"(r3b)
                : "v"(trb) : "memory");
            __builtin_amdgcn_sched_barrier(0);
            short8 v0 = __builtin_shufflevector(r0a, r0b, 0,1,2,3,4,5,6,7);
            short8 v1 = __builtin_shufflevector(r1a, r1b, 0,1,2,3,4,5,6,7);
            short8 v2 = __builtin_shufflevector(r2a, r2b, 0,1,2,3,4,5,6,7);
            short8 v3 = __builtin_shufflevector(r3a, r3b, 0,1,2,3,4,5,6,7);
            __builtin_amdgcn_s_setprio(1);
            oA[0] = __builtin_amdgcn_mfma_f32_16x16x32_bf16(v0, pfA, oA[0], 0,0,0);
            oB[0] = __builtin_amdgcn_mfma_f32_16x16x32_bf16(v0, pfB, oB[0], 0,0,0);
            oA[1] = __builtin_amdgcn_mfma_f32_16x16x32_bf16(v1, pfA, oA[1], 0,0,0);
            oB[1] = __builtin_amdgcn_mfma_f32_16x16x32_bf16(v1, pfB, oB[1], 0,0,0);
            oA[2] = __builtin_amdgcn_mfma_f32_16x16x32_bf16(v2, pfA, oA[2], 0,0,0);
            oB[2] = __builtin_amdgcn_mfma_f32_16x16x32_bf16(v2, pfB, oB[2], 0,0,0);
            oA[3] = __builtin_amdgcn_mfma_f32_16x16x32_bf16(v3, pfA, oA[3], 0,0,0);
            oB[3] = __builtin_amdgcn_mfma_f32_16x16x32_bf16(v3, pfB, oB[3], 0,0,0);
            __builtin_amdgcn_s_setprio(0);
        }
        __builtin_amdgcn_wave_barrier();

        // ================= half 1: toks 32..63 =================
#pragma unroll
        for (int tgl = 0; tgl < 2; ++tgl) {
            const int tg = 2 + tgl;        // global tg = 2,3
            unsigned k0a, k1a, k0b, k1b;
            asm volatile("v_cvt_pk_bf16_f32 %0, %1, %2" : "=v"(k0a) : "v"(pA[tg*4+0]), "v"(pA[tg*4+1]));
            asm volatile("v_cvt_pk_bf16_f32 %0, %1, %2" : "=v"(k1a) : "v"(pA[tg*4+2]), "v"(pA[tg*4+3]));
            asm volatile("v_cvt_pk_bf16_f32 %0, %1, %2" : "=v"(k0b) : "v"(pB[tg*4+0]), "v"(pB[tg*4+1]));
            asm volatile("v_cvt_pk_bf16_f32 %0, %1, %2" : "=v"(k1b) : "v"(pB[tg*4+2]), "v"(pB[tg*4+3]));
            const int boff = ((((tgl << 1) | (l4 >> 1)) ^ (l15 & 3)) << 4) + pwoff;
            *(uint2*)(Pw + l15*64        + boff) = make_uint2(k0a, k1a);
            *(uint2*)(Pw + (16 + l15)*64 + boff) = make_uint2(k0b, k1b);
        }
        __builtin_amdgcn_wave_barrier();
        {
            const short8 pfA = *(const short8*)(Pw + l15*64        + prd);
            const short8 pfB = *(const short8*)(Pw + (16 + l15)*64 + prd);
            asm volatile(
                "ds_read_b64_tr_b16 %0, %8 offset:4096\n\t"
                "ds_read_b64_tr_b16 %1, %8 offset:4608\n\t"
                "ds_read_b64_tr_b16 %2, %8 offset:4224\n\t"
                "ds_read_b64_tr_b16 %3, %8 offset:4736\n\t"
                "ds_read_b64_tr_b16 %4, %8 offset:4352\n\t"
                "ds_read_b64_tr_b16 %5, %8 offset:4864\n\t"
                "ds_read_b64_tr_b16 %6, %8 offset:4480\n\t"
                "ds_read_b64_tr_b16 %7, %8 offset:4992\n\t"
                "s_waitcnt lgkmcnt(0)"
                : "=&v"(r0a), "=&v"(r0b), "=&v"(r1a), "=&v"(r1b),
                  "=&v"(r2a), "=&v"(r2b), "=&v"(r3a), "=&v"(r3b)
                : "v"(trb) : "memory");
            __builtin_amdgcn_sched_barrier(0);
            short8 v0 = __builtin_shufflevector(r0a, r0b, 0,1,2,3,4,5,6,7);
            short8 v1 = __builtin_shufflevector(r1a, r1b, 0,1,2,3,4,5,6,7);
            short8 v2 = __builtin_shufflevector(r2a, r2b, 0,1,2,3,4,5,6,7);
            short8 v3 = __builtin_shufflevector(r3a, r3b, 0,1,2,3,4,5,6,7);
            __builtin_amdgcn_s_setprio(1);
            oA[0] = __builtin_amdgcn_mfma_f32_16x16x32_bf16(v0, pfA, oA[0], 0,0,0);
            oB[0] = __builtin_amdgcn_mfma_f32_16x16x32_bf16(v0, pfB, oB[0], 0,0,0);
            oA[1] = __builtin_amdgcn_mfma_f32_16x16x32_bf16(v1, pfA, oA[1], 0,0,0);
            oB[1] = __builtin_amdgcn_mfma_f32_16x16x32_bf16(v1, pfB, oB[1], 0,0,0);
            oA[2] = __builtin_amdgcn_mfma_f32_16x16x32_bf16(v2, pfA, oA[2], 0,0,0);
            oB[2] = __builtin_amdgcn_mfma_f32_16x16x32_bf16(v2, pfB, oB[2], 0,0,0);
            oA[3] = __builtin_amdgcn_mfma_f32_16x16x32_bf16(v3, pfA, oA[3], 0,0,0);
            oB[3] = __builtin_amdgcn_mfma_f32_16x16x32_bf16(v3, pfB, oB[3], 0,0,0);
            __builtin_amdgcn_s_setprio(0);
        }
    }

    // ---- epilogue: single cross-lane reduce of l, then store O^T ----
    const float liA = 1.f / red_sum(lA);
    const float liB = 1.f / red_sum(lB);
    const int b = bh / NH, h = bh % NH;
    const int qA = q0 + w*32 + l15;
    const int qB = qA + 16;
    if (qA < NTOK) {
        unsigned short* p = Obf + ((size_t)b*NTOK + qA)*DIM + h*HD + l4*4;
#pragma unroll
        for (int dg = 0; dg < 4; ++dg) {
            uint2 pk;
            pk.x = f2bf(oA[dg][0]*liA) | (f2bf(oA[dg][1]*liA) << 16);
            pk.y = f2bf(oA[dg][2]*liA) | (f2bf(oA[dg][3]*liA) << 16);
            *(uint2*)(p + dg*16) = pk;
        }
    }
    if (qB < NTOK) {
        unsigned short* p = Obf + ((size_t)b*NTOK + qB)*DIM + h*HD + l4*4;
#pragma unroll
        for (int dg = 0; dg < 4; ++dg) {
            uint2 pk;
            pk.x = f2bf(oB[dg][0]*liB) | (f2bf(oB[dg][1]*liB) << 16);
            pk.y = f2bf(oB[dg][2]*liB) | (f2bf(oB[dg][3]*liB) << 16);
            *(uint2*)(p + dg*16) = pk;
        }
    }
}

// ------------------------------------------------------------------
// Kernel 3: proj GEMM (feat=768, tok=16400), fp32 out + bias.
// 1D grid 774, XCD-chunked (6 D0-blocks per token panel on one XCD).
// ------------------------------------------------------------------
__global__ __launch_bounds__(256) void proj_gemm_kernel(
    const unsigned short* __restrict__ Wpb, const unsigned short* __restrict__ Obf,
    const float* __restrict__ bp, float* __restrict__ out)
{
    __shared__ __align__(16) short Ws[128*64];
    __shared__ __align__(16) short Xs[128*64];
    f32x4 acc[4][4] = {};
    const int tid = threadIdx.x;

    // bijective XCD swizzle: 774 = 6 D0 x 129 T0-groups
    const int dd0 = blockIdx.x;
    int xc, j;
    if (dd0 >= 768) { xc = 0; j = 96 + (dd0 - 768); }
    else            { xc = dd0 & 7; j = dd0 >> 3; }
    const int D0 = (j % 6) * 128;
    const int T0 = (xc + 8 * (j / 6)) * 128;

    gemm_core(Wpb, Obf, D0, T0, MTOT - 1, Ws, Xs, acc, tid);

    const int lane = tid & 63;
    const int wu = tid >> 6, wr = wu >> 1, wc = wu & 1;
    const int l4 = lane >> 4, l15 = lane & 15;

    unsigned mArr[4];
    bool vArr[4];
#pragma unroll
    for (int fn = 0; fn < 4; ++fn) {
        unsigned m = T0 + wc*64 + fn*16 + l15;
        mArr[fn] = m;
        vArr[fn] = m < MTOT;
    }
#pragma unroll
    for (int fm = 0; fm < 4; ++fm) {
        const int nG = D0 + wr*64 + fm*16 + l4*4;
        const float4 bias = *(const float4*)&bp[nG];
#pragma unroll
        for (int fn = 0; fn < 4; ++fn) {
            if (!vArr[fn]) continue;
            f32x4 a = acc[fm][fn];
            float4 v = make_float4(a[0]+bias.x, a[1]+bias.y, a[2]+bias.z, a[3]+bias.w);
            *(float4*)&out[(size_t)mArr[fn]*DIM + nG] = v;
        }
    }
}

extern "C" void kernel_launch(void* const* d_in, const int* in_sizes, int n_in,
                              void* d_out, int out_size, void* d_ws, size_t ws_size,
                              hipStream_t stream)
{
    const float* x     = (const float*)d_in[0];
    const float* Wqkv  = (const float*)d_in[1];
    const float* Wp    = (const float*)d_in[2];
    const float* bp    = (const float*)d_in[3];
    const float* freqs = (const float*)d_in[4];
    float* out = (float*)d_out;

    const size_t SZ = (size_t)BATCH * NH * NTOK * HD;  // 12,595,200
    unsigned short* Qb  = (unsigned short*)d_ws;
    unsigned short* Kb  = Qb + SZ;
    unsigned short* Vb  = Kb + SZ;
    unsigned short* Obf = Vb + SZ;
    unsigned short* xb  = Obf + SZ;
    unsigned short* Wqb = xb + SZ;
    unsigned short* Wpb = Wqb + (size_t)QKVD * DIM;
    float2*         tab = (float2*)(Wpb + (size_t)DIM * DIM);

    cvt_bf16_kernel<<<2048, 256, 0, stream>>>(x, Wqkv, Wp, xb, Wqb, Wpb);
    rope_tab_kernel<<<1536, 256, 0, stream>>>(freqs, tab);
    qkv_gemm_kernel<<<2322, 256, 0, stream>>>(Wqb, xb, tab, Qb, Kb, Vb);
    attn_mfma_kernel<<<1728, 256, 0, stream>>>(Qb, Kb, Vb, Obf);
    proj_gemm_kernel<<<774, 256, 0, stream>>>(Wpb, Obf, bp, out);
}

// Round 12
// 265.687 us; speedup vs baseline: 1.1181x; 1.0099x over previous
//
#include <hip/hip_runtime.h>
#include <math.h>

#define DIM     768
#define NH      12
#define HD      64
#define NTOK    1025
#define BATCH   16
#define MTOT    (BATCH * NTOK)        // 16400
#define QKVD    (3 * DIM)             // 2304

typedef short  short8  __attribute__((ext_vector_type(8)));
typedef short  short4v __attribute__((ext_vector_type(4)));
typedef float  f32x4   __attribute__((ext_vector_type(4)));

typedef const __attribute__((address_space(1))) void gvoid_t;
typedef __attribute__((address_space(3)))       void lvoid_t;
typedef __attribute__((address_space(3)))       char lchar_t;
#define GLD16(gsrc, ldst) __builtin_amdgcn_global_load_lds( \
    (gvoid_t*)(gsrc), (lvoid_t*)(ldst), 16, 0, 0)

static __device__ __forceinline__ unsigned int f2bf(float f) {
    unsigned int u = __float_as_uint(f);
    u += 0x7FFFu + ((u >> 16) & 1u);      // RNE
    return u >> 16;
}

static __device__ __forceinline__ float red_sum(float x) {
    x += __shfl_xor(x, 16);
    x += __shfl_xor(x, 32);
    return x;
}

// ------------------------------------------------------------------
// Kernel 0: fp32 -> bf16 conversion of x, W_qkv, W_proj
// ------------------------------------------------------------------
__device__ __forceinline__ void cvt8(const float* __restrict__ src,
                                     unsigned short* __restrict__ dst, int i) {
    float4 a = *(const float4*)(src + (size_t)i*8);
    float4 b = *(const float4*)(src + (size_t)i*8 + 4);
    uint4 pk;
    pk.x = f2bf(a.x) | (f2bf(a.y) << 16);
    pk.y = f2bf(a.z) | (f2bf(a.w) << 16);
    pk.z = f2bf(b.x) | (f2bf(b.y) << 16);
    pk.w = f2bf(b.z) | (f2bf(b.w) << 16);
    *(uint4*)(dst + (size_t)i*8) = pk;
}

__global__ __launch_bounds__(256) void cvt_bf16_kernel(
    const float* __restrict__ x, const float* __restrict__ Wq,
    const float* __restrict__ Wp,
    unsigned short* __restrict__ xb, unsigned short* __restrict__ Wqb,
    unsigned short* __restrict__ Wpb)
{
    const int stride = gridDim.x * blockDim.x;
    const int tid = blockIdx.x * blockDim.x + threadIdx.x;
    for (int i = tid; i < MTOT*DIM/8;  i += stride) cvt8(x,  xb,  i);
    for (int i = tid; i < QKVD*DIM/8;  i += stride) cvt8(Wq, Wqb, i);
    for (int i = tid; i < DIM*DIM/8;   i += stride) cvt8(Wp, Wpb, i);
}

// ------------------------------------------------------------------
// Kernel 0b: RoPE cos/sin table  [h][n1][pair] float2, 393216 entries
// ------------------------------------------------------------------
__global__ __launch_bounds__(256) void rope_tab_kernel(
    const float* __restrict__ freqs, float2* __restrict__ tab)
{
    const int gid = blockIdx.x * 256 + threadIdx.x;     // < 393216
    const int p  = gid & 31;
    const int n1 = (gid >> 5) & 1023;
    const int h  = gid >> 15;
    const float tx = (float)(n1 & 31), ty = (float)(n1 >> 5);
    const float ang = tx * freqs[h*32 + p] + ty * freqs[384 + h*32 + p];
    float s, c;
    sincosf(ang, &s, &c);
    tab[gid] = make_float2(c, s);
}

// ------------------------------------------------------------------
// Shared bf16 MFMA GEMM core: C[feat][tok] = W[feat][k] * X[tok][k]^T
// K=768, tile 128x128, BK=64, 256 threads (4 waves 2x2, each 64x64).
// ------------------------------------------------------------------
__device__ __forceinline__ void gemm_core(
    const unsigned short* __restrict__ Wb,
    const unsigned short* __restrict__ Xb,
    int D0, int T0, int maxXrow,
    short* Ws, short* Xs, f32x4 acc[4][4], int tid)
{
    const int lane = tid & 63;
    const int wu   = __builtin_amdgcn_readfirstlane(tid >> 6);
    const int wr   = wu >> 1, wc = wu & 1;
    const int l4   = lane >> 4, l15 = lane & 15;

    const int srow = lane >> 3;
    const int schk = (lane & 7) ^ srow;
    const unsigned short* wsrc[4];
    const unsigned short* xsrc[4];
#pragma unroll
    for (int i = 0; i < 4; ++i) {
        int r = wu*32 + i*8 + srow;
        wsrc[i] = Wb + (size_t)(D0 + r) * DIM + schk*8;
        int xr = T0 + r; if (xr > maxXrow) xr = maxXrow;
        xsrc[i] = Xb + (size_t)xr * DIM + schk*8;
    }

    for (int kt = 0; kt < DIM/64; ++kt) {
        __syncthreads();
#pragma unroll
        for (int i = 0; i < 4; ++i) {
            GLD16(wsrc[i] + kt*64, &Ws[(wu*4 + i) * 512]);
            GLD16(xsrc[i] + kt*64, &Xs[(wu*4 + i) * 512]);
        }
        __syncthreads();

        short8 wf[4][2], xf[4][2];
#pragma unroll
        for (int f = 0; f < 4; ++f) {
            const int rw = wr*64 + f*16 + l15;
            const int rx = wc*64 + f*16 + l15;
#pragma unroll
            for (int kf = 0; kf < 2; ++kf) {
                wf[f][kf] = *(const short8*)&Ws[rw*64 + (((kf*4 + l4) ^ (rw & 7)) << 3)];
                xf[f][kf] = *(const short8*)&Xs[rx*64 + (((kf*4 + l4) ^ (rx & 7)) << 3)];
            }
        }
        __builtin_amdgcn_s_setprio(1);
#pragma unroll
        for (int kf = 0; kf < 2; ++kf)
#pragma unroll
            for (int fm = 0; fm < 4; ++fm)
#pragma unroll
                for (int fn = 0; fn < 4; ++fn)
                    acc[fm][fn] = __builtin_amdgcn_mfma_f32_16x16x32_bf16(
                        wf[fm][kf], xf[fn][kf], acc[fm][fn], 0, 0, 0);
        __builtin_amdgcn_s_setprio(0);
    }
}

// ------------------------------------------------------------------
// Kernel 1: QKV GEMM + fused RoPE (table), bf16 out to Q/K/V (B,H,N,64)
// Q pre-scaled by scale*log2(e). 1D grid 2322, XCD-chunked so all 18
// D0-blocks of one token panel land on one XCD (x-panel L2 reuse).
// ------------------------------------------------------------------
__global__ __launch_bounds__(256) void qkv_gemm_kernel(
    const unsigned short* __restrict__ Wqb, const unsigned short* __restrict__ xb,
    const float2* __restrict__ tab,
    unsigned short* __restrict__ Qb, unsigned short* __restrict__ Kb,
    unsigned short* __restrict__ Vb)
{
    __shared__ __align__(16) short Ws[128*64];
    __shared__ __align__(16) short Xs[128*64];
    f32x4 acc[4][4] = {};
    const int tid = threadIdx.x;

    // bijective XCD swizzle: 2322 = 18 D0 x 129 T0-groups
    const int dd0 = blockIdx.x;
    int xc, j;
    if (dd0 >= 2304) { xc = 0; j = 288 + (dd0 - 2304); }
    else             { xc = dd0 & 7; j = dd0 >> 3; }
    const int D0 = (j % 18) * 128;
    const int T0 = (xc + 8 * (j / 18)) * 128;

    gemm_core(Wqb, xb, D0, T0, MTOT - 1, Ws, Xs, acc, tid);

    const int lane = tid & 63;
    const int wu = tid >> 6, wr = wu >> 1, wc = wu & 1;
    const int l4 = lane >> 4, l15 = lane & 15;
    const int which = D0 / DIM;
    unsigned short* dst = (which == 0) ? Qb : (which == 1) ? Kb : Vb;
    const float qs = (which == 0) ? 0.125f * 1.44269504089f : 1.f;

    unsigned bArr[4], nArr[4];
    bool vArr[4];
#pragma unroll
    for (int fn = 0; fn < 4; ++fn) {
        unsigned m = T0 + wc*64 + fn*16 + l15;
        vArr[fn] = m < MTOT;
        bArr[fn] = m / NTOK;
        nArr[fn] = m - bArr[fn]*NTOK;
    }
#pragma unroll
    for (int fm = 0; fm < 4; ++fm) {
        const int hcol = (D0 % DIM) + wr*64 + fm*16 + l4*4;
        const int h = hcol >> 6, dd = hcol & 63;
        const int p0 = dd >> 1;                    // even
#pragma unroll
        for (int fn = 0; fn < 4; ++fn) {
            if (!vArr[fn]) continue;
            f32x4 a = acc[fm][fn];
            const int n = nArr[fn];
            if (which < 2) {                       // RoPE on Q,K (not CLS)
                int n1 = n > 0 ? n - 1 : 0;
                float4 cs = *(const float4*)&tab[(size_t)(h*1024 + n1)*32 + p0];
                if (n == 0) cs = make_float4(1.f, 0.f, 1.f, 0.f);
                float e0 = a[0], od0 = a[1], e1 = a[2], od1 = a[3];
                a[0] = e0*cs.x - od0*cs.y;  a[1] = e0*cs.y + od0*cs.x;
                a[2] = e1*cs.z - od1*cs.w;  a[3] = e1*cs.w + od1*cs.z;
            }
            uint2 pk;
            pk.x = f2bf(a[0]*qs) | (f2bf(a[1]*qs) << 16);
            pk.y = f2bf(a[2]*qs) | (f2bf(a[3]*qs) << 16);
            *(uint2*)&dst[((size_t)(bArr[fn]*NH + h)*NTOK + n)*HD + dd] = pk;
        }
    }
}

// ------------------------------------------------------------------
// Kernel 2: bf16 MFMA flash attention (R10 proven config): V via GLD
// subtiles + ds_read_b64_tr_b16, P per-wave [32q][64tok], O^T, no max
// tracking, dbuf K/V, one barrier/tile, grid 1728 XCD-chunked.
// ------------------------------------------------------------------
__global__ __launch_bounds__(256) void attn_mfma_kernel(
    const unsigned short* __restrict__ Qb,
    const unsigned short* __restrict__ Kb,
    const unsigned short* __restrict__ Vb,
    unsigned short* __restrict__ Obf)
{
    __shared__ __align__(16) char KsR[2][8192];   // [tok][64d], chunk^(tok&7)
    __shared__ __align__(16) char VtR[2][8192];   // [T=16][D=4][t=4][dd=16] bf16
    __shared__ __align__(16) char PsR[4][4096];   // per wave [32q][64tok], swz

    const int tid  = threadIdx.x;
    const int lane = tid & 63;
    const int w    = __builtin_amdgcn_readfirstlane(tid >> 6);
    const int l4   = lane >> 4, l15 = lane & 15, l7 = lane & 7;

    const int d    = blockIdx.x;
    const int xcd  = d & 7;
    const int s    = d >> 3;                 // 0..215
    const int bh   = xcd * 24 + s / 9;
    const int q0   = (s % 9) * 128;
    const size_t base = (size_t)bh * NTOK * HD;

    // Q frags (pre-scaled by scale*log2e)
    short8 qf[2][2];
#pragma unroll
    for (int qg = 0; qg < 2; ++qg) {
        int qr = q0 + w*32 + qg*16 + l15;
        int qrc = qr < NTOK ? qr : NTOK - 1;
        qf[qg][0] = *(const short8*)(Qb + base + (size_t)qrc*HD + l4*8);
        qf[qg][1] = *(const short8*)(Qb + base + (size_t)qrc*HD + 32 + l4*8);
    }

    float lA = 0.f, lB = 0.f;
    f32x4 oA[4] = {}, oB[4] = {};          // O^T: row=d (l4,r), col=q (l15)

    // K staging params
    const int ktokb = tid >> 3;                  // 0..31
    const int kchk  = tid & 7;
    // V staging params: chunk c -> (T,D,t,h8) subtile source
    const int c0 = tid, c1 = tid + 256;
    const int vt0 = ((c0 >> 5) << 2) | ((c0 >> 1) & 3);   // tile-local tok
    const int vt1 = ((c1 >> 5) << 2) | ((c1 >> 1) & 3);
    const int vo0 = (((c0 >> 3) & 3) << 4) | ((c0 & 1) << 3); // d offset
    const int vo1 = (((c1 >> 3) & 3) << 4) | ((c1 & 1) << 3);
    char* Pw = &PsR[w][0];

    // ---- prologue: stage tile 0 (K + V, all GLD) ----
#pragma unroll
    for (int i = 0; i < 2; ++i) {
        int tok = ktokb + i*32;
        int sc = kchk ^ (tok & 7);
        GLD16(Kb + base + (size_t)tok*HD + sc*8, &KsR[0][w*1024 + i*4096]);
    }
    GLD16(Vb + base + (size_t)vt0*HD + vo0, &VtR[0][w*1024]);
    GLD16(Vb + base + (size_t)vt1*HD + vo1, &VtR[0][4096 + w*1024]);

    for (int kt = 0; kt < 17; ++kt) {
        const int buf = kt & 1;
        __syncthreads();   // tile kt staged & visible (drains all GLDs)

        if (kt < 16) {
            const int nb = buf ^ 1;
#pragma unroll
            for (int i = 0; i < 2; ++i) {
                int tok = ktokb + i*32;
                int gk = (kt+1)*64 + tok; if (gk > NTOK-1) gk = NTOK-1;
                int sc = kchk ^ (tok & 7);
                GLD16(Kb + base + (size_t)gk*HD + sc*8, &KsR[nb][w*1024 + i*4096]);
            }
            int g0 = (kt+1)*64 + vt0; if (g0 > NTOK-1) g0 = NTOK-1;
            int g1 = (kt+1)*64 + vt1; if (g1 > NTOK-1) g1 = NTOK-1;
            GLD16(Vb + base + (size_t)g0*HD + vo0, &VtR[nb][w*1024]);
            GLD16(Vb + base + (size_t)g1*HD + vo1, &VtR[nb][4096 + w*1024]);
        }

        // ---- S^T = K @ Q^T  (lane: q = l15, tok = tg*16 + l4*4 + r) ----
        f32x4 sA[4] = {}, sB[4] = {};
        __builtin_amdgcn_s_setprio(1);
#pragma unroll
        for (int tg = 0; tg < 4; ++tg) {
            const int row = tg*16 + l15;
            short8 ka0 = *(const short8*)(&KsR[buf][0] + row*128 + ((l4 ^ l7) << 4));
            short8 ka1 = *(const short8*)(&KsR[buf][0] + row*128 + (((4 + l4) ^ l7) << 4));
            sA[tg] = __builtin_amdgcn_mfma_f32_16x16x32_bf16(ka0, qf[0][0], sA[tg], 0,0,0);
            sA[tg] = __builtin_amdgcn_mfma_f32_16x16x32_bf16(ka1, qf[0][1], sA[tg], 0,0,0);
            sB[tg] = __builtin_amdgcn_mfma_f32_16x16x32_bf16(ka0, qf[1][0], sB[tg], 0,0,0);
            sB[tg] = __builtin_amdgcn_mfma_f32_16x16x32_bf16(ka1, qf[1][1], sB[tg], 0,0,0);
        }
        __builtin_amdgcn_s_setprio(0);

        // ---- p = exp2(s); mask only last tile (p=0 protects clamped V) ----
        float pA[16], pB[16];
        if (kt == 16) {
#pragma unroll
            for (int tg = 0; tg < 4; ++tg)
#pragma unroll
                for (int r = 0; r < 4; ++r) {
                    int tok = 1024 + tg*16 + l4*4 + r;
                    float sa = (tok > 1024) ? -3e38f : sA[tg][r];
                    float sb = (tok > 1024) ? -3e38f : sB[tg][r];
                    pA[tg*4+r] = __builtin_exp2f(sa);
                    pB[tg*4+r] = __builtin_exp2f(sb);
                }
        } else {
#pragma unroll
            for (int tg = 0; tg < 4; ++tg)
#pragma unroll
                for (int r = 0; r < 4; ++r) {
                    pA[tg*4+r] = __builtin_exp2f(sA[tg][r]);
                    pB[tg*4+r] = __builtin_exp2f(sB[tg][r]);
                }
        }
        float psA = 0.f, psB = 0.f;
#pragma unroll
        for (int i = 0; i < 16; ++i) { psA += pA[i]; psB += pB[i]; }
        lA += psA;
        lB += psB;

        // ---- P -> LDS (packed bf16 pairs, b64 writes, swizzled) ----
#pragma unroll
        for (int tg = 0; tg < 4; ++tg) {
            unsigned k0a, k1a, k0b, k1b;
            asm volatile("v_cvt_pk_bf16_f32 %0, %1, %2" : "=v"(k0a) : "v"(pA[tg*4+0]), "v"(pA[tg*4+1]));
            asm volatile("v_cvt_pk_bf16_f32 %0, %1, %2" : "=v"(k1a) : "v"(pA[tg*4+2]), "v"(pA[tg*4+3]));
            asm volatile("v_cvt_pk_bf16_f32 %0, %1, %2" : "=v"(k0b) : "v"(pB[tg*4+0]), "v"(pB[tg*4+1]));
            asm volatile("v_cvt_pk_bf16_f32 %0, %1, %2" : "=v"(k1b) : "v"(pB[tg*4+2]), "v"(pB[tg*4+3]));
            const int chk = (((tg*2 + (l4 >> 1)) ^ l7) << 4) + (l4 & 1)*8;
            *(uint2*)(Pw + l15*128      + chk) = make_uint2(k0a, k1a);
            *(uint2*)(Pw + (16+l15)*128 + chk) = make_uint2(k0b, k1b);
        }
        __builtin_amdgcn_wave_barrier();

        const short8 pf00 = *(const short8*)(Pw + l15*128      + ((l4 ^ l7) << 4));
        const short8 pf01 = *(const short8*)(Pw + l15*128      + (((4+l4) ^ l7) << 4));
        const short8 pf10 = *(const short8*)(Pw + (16+l15)*128 + ((l4 ^ l7) << 4));
        const short8 pf11 = *(const short8*)(Pw + (16+l15)*128 + (((4+l4) ^ l7) << 4));

        // ---- O^T += V^T @ P via hardware transpose reads ----
        const unsigned trb = (unsigned)(unsigned long long)
            (lchar_t*)(&VtR[buf][0] + (l4 << 10) + (l15 << 3));
        short4v r0a, r0b, r1a, r1b, r2a, r2b, r3a, r3b;

        // toks 0..31 (half 0): offset = dg*128 + c*512
        asm volatile(
            "ds_read_b64_tr_b16 %0, %8 offset:0\n\t"
            "ds_read_b64_tr_b16 %1, %8 offset:512\n\t"
            "ds_read_b64_tr_b16 %2, %8 offset:128\n\t"
            "ds_read_b64_tr_b16 %3, %8 offset:640\n\t"
            "ds_read_b64_tr_b16 %4, %8 offset:256\n\t"
            "ds_read_b64_tr_b16 %5, %8 offset:768\n\t"
            "ds_read_b64_tr_b16 %6, %8 offset:384\n\t"
            "ds_read_b64_tr_b16 %7, %8 offset:896\n\t"
            "s_waitcnt lgkmcnt(0)"
            : "=&v"(r0a), "=&v"(r0b), "=&v"(r1a), "=&v"(r1b),
              "=&v"(r2a), "=&v"(r2b), "=&v"(r3a), "=&v"(r3b)
            : "v"(trb) : "memory");
        __builtin_amdgcn_sched_barrier(0);
        {
            short8 v0 = __builtin_shufflevector(r0a, r0b, 0,1,2,3,4,5,6,7);
            short8 v1 = __builtin_shufflevector(r1a, r1b, 0,1,2,3,4,5,6,7);
            short8 v2 = __builtin_shufflevector(r2a, r2b, 0,1,2,3,4,5,6,7);
            short8 v3 = __builtin_shufflevector(r3a, r3b, 0,1,2,3,4,5,6,7);
            __builtin_amdgcn_s_setprio(1);
            oA[0] = __builtin_amdgcn_mfma_f32_16x16x32_bf16(v0, pf00, oA[0], 0,0,0);
            oB[0] = __builtin_amdgcn_mfma_f32_16x16x32_bf16(v0, pf10, oB[0], 0,0,0);
            oA[1] = __builtin_amdgcn_mfma_f32_16x16x32_bf16(v1, pf00, oA[1], 0,0,0);
            oB[1] = __builtin_amdgcn_mfma_f32_16x16x32_bf16(v1, pf10, oB[1], 0,0,0);
            oA[2] = __builtin_amdgcn_mfma_f32_16x16x32_bf16(v2, pf00, oA[2], 0,0,0);
            oB[2] = __builtin_amdgcn_mfma_f32_16x16x32_bf16(v2, pf10, oB[2], 0,0,0);
            oA[3] = __builtin_amdgcn_mfma_f32_16x16x32_bf16(v3, pf00, oA[3], 0,0,0);
            oB[3] = __builtin_amdgcn_mfma_f32_16x16x32_bf16(v3, pf10, oB[3], 0,0,0);
            __builtin_amdgcn_s_setprio(0);
        }
        // toks 32..63 (half 1): offsets + 4096
        asm volatile(
            "ds_read_b64_tr_b16 %0, %8 offset:4096\n\t"
            "ds_read_b64_tr_b16 %1, %8 offset:4608\n\t"
            "ds_read_b64_tr_b16 %2, %8 offset:4224\n\t"
            "ds_read_b64_tr_b16 %3, %8 offset:4736\n\t"
            "ds_read_b64_tr_b16 %4, %8 offset:4352\n\t"
            "ds_read_b64_tr_b16 %5, %8 offset:4864\n\t"
            "ds_read_b64_tr_b16 %6, %8 offset:4480\n\t"
            "ds_read_b64_tr_b16 %7, %8 offset:4992\n\t"
            "s_waitcnt lgkmcnt(0)"
            : "=&v"(r0a), "=&v"(r0b), "=&v"(r1a), "=&v"(r1b),
              "=&v"(r2a), "=&v"(r2b), "=&v"(r3a), "=&v"(r3b)
            : "v"(trb) : "memory");
        __builtin_amdgcn_sched_barrier(0);
        {
            short8 v0 = __builtin_shufflevector(r0a, r0b, 0,1,2,3,4,5,6,7);
            short8 v1 = __builtin_shufflevector(r1a, r1b, 0,1,2,3,4,5,6,7);
            short8 v2 = __builtin_shufflevector(r2a, r2b, 0,1,2,3,4,5,6,7);
            short8 v3 = __builtin_shufflevector(r3a, r3b, 0,1,2,3,4,5,6,7);
            __builtin_amdgcn_s_setprio(1);
            oA[0] = __builtin_amdgcn_mfma_f32_16x16x32_bf16(v0, pf01, oA[0], 0,0,0);
            oB[0] = __builtin_amdgcn_mfma_f32_16x16x32_bf16(v0, pf11, oB[0], 0,0,0);
            oA[1] = __builtin_amdgcn_mfma_f32_16x16x32_bf16(v1, pf01, oA[1], 0,0,0);
            oB[1] = __builtin_amdgcn_mfma_f32_16x16x32_bf16(v1, pf11, oB[1], 0,0,0);
            oA[2] = __builtin_amdgcn_mfma_f32_16x16x32_bf16(v2, pf01, oA[2], 0,0,0);
            oB[2] = __builtin_amdgcn_mfma_f32_16x16x32_bf16(v2, pf11, oB[2], 0,0,0);
            oA[3] = __builtin_amdgcn_mfma_f32_16x16x32_bf16(v3, pf01, oA[3], 0,0,0);
            oB[3] = __builtin_amdgcn_mfma_f32_16x16x32_bf16(v3, pf11, oB[3], 0,0,0);
            __builtin_amdgcn_s_setprio(0);
        }
    }

    // ---- epilogue: single cross-lane reduce of l, then store O^T ----
    const float liA = 1.f / red_sum(lA);
    const float liB = 1.f / red_sum(lB);
    const int b = bh / NH, h = bh % NH;
    const int qA = q0 + w*32 + l15;
    const int qB = qA + 16;
    if (qA < NTOK) {
        unsigned short* p = Obf + ((size_t)b*NTOK + qA)*DIM + h*HD + l4*4;
#pragma unroll
        for (int dg = 0; dg < 4; ++dg) {
            uint2 pk;
            pk.x = f2bf(oA[dg][0]*liA) | (f2bf(oA[dg][1]*liA) << 16);
            pk.y = f2bf(oA[dg][2]*liA) | (f2bf(oA[dg][3]*liA) << 16);
            *(uint2*)(p + dg*16) = pk;
        }
    }
    if (qB < NTOK) {
        unsigned short* p = Obf + ((size_t)b*NTOK + qB)*DIM + h*HD + l4*4;
#pragma unroll
        for (int dg = 0; dg < 4; ++dg) {
            uint2 pk;
            pk.x = f2bf(oB[dg][0]*liB) | (f2bf(oB[dg][1]*liB) << 16);
            pk.y = f2bf(oB[dg][2]*liB) | (f2bf(oB[dg][3]*liB) << 16);
            *(uint2*)(p + dg*16) = pk;
        }
    }
}

// ------------------------------------------------------------------
// Kernel 3: proj GEMM (feat=768, tok=16400), fp32 out + bias.
// 1D grid 774, XCD-chunked (6 D0-blocks per token panel on one XCD).
// ------------------------------------------------------------------
__global__ __launch_bounds__(256) void proj_gemm_kernel(
    const unsigned short* __restrict__ Wpb, const unsigned short* __restrict__ Obf,
    const float* __restrict__ bp, float* __restrict__ out)
{
    __shared__ __align__(16) short Ws[128*64];
    __shared__ __align__(16) short Xs[128*64];
    f32x4 acc[4][4] = {};
    const int tid = threadIdx.x;

    // bijective XCD swizzle: 774 = 6 D0 x 129 T0-groups
    const int dd0 = blockIdx.x;
    int xc, j;
    if (dd0 >= 768) { xc = 0; j = 96 + (dd0 - 768); }
    else            { xc = dd0 & 7; j = dd0 >> 3; }
    const int D0 = (j % 6) * 128;
    const int T0 = (xc + 8 * (j / 6)) * 128;

    gemm_core(Wpb, Obf, D0, T0, MTOT - 1, Ws, Xs, acc, tid);

    const int lane = tid & 63;
    const int wu = tid >> 6, wr = wu >> 1, wc = wu & 1;
    const int l4 = lane >> 4, l15 = lane & 15;

    unsigned mArr[4];
    bool vArr[4];
#pragma unroll
    for (int fn = 0; fn < 4; ++fn) {
        unsigned m = T0 + wc*64 + fn*16 + l15;
        mArr[fn] = m;
        vArr[fn] = m < MTOT;
    }
#pragma unroll
    for (int fm = 0; fm < 4; ++fm) {
        const int nG = D0 + wr*64 + fm*16 + l4*4;
        const float4 bias = *(const float4*)&bp[nG];
#pragma unroll
        for (int fn = 0; fn < 4; ++fn) {
            if (!vArr[fn]) continue;
            f32x4 a = acc[fm][fn];
            float4 v = make_float4(a[0]+bias.x, a[1]+bias.y, a[2]+bias.z, a[3]+bias.w);
            *(float4*)&out[(size_t)mArr[fn]*DIM + nG] = v;
        }
    }
}

extern "C" void kernel_launch(void* const* d_in, const int* in_sizes, int n_in,
                              void* d_out, int out_size, void* d_ws, size_t ws_size,
                              hipStream_t stream)
{
    const float* x     = (const float*)d_in[0];
    const float* Wqkv  = (const float*)d_in[1];
    const float* Wp    = (const float*)d_in[2];
    const float* bp    = (const float*)d_in[3];
    const float* freqs = (const float*)d_in[4];
    float* out = (float*)d_out;

    const size_t SZ = (size_t)BATCH * NH * NTOK * HD;  // 12,595,200
    unsigned short* Qb  = (unsigned short*)d_ws;
    unsigned short* Kb  = Qb + SZ;
    unsigned short* Vb  = Kb + SZ;
    unsigned short* Obf = Vb + SZ;
    unsigned short* xb  = Obf + SZ;
    unsigned short* Wqb = xb + SZ;
    unsigned short* Wpb = Wqb + (size_t)QKVD * DIM;
    float2*         tab = (float2*)(Wpb + (size_t)DIM * DIM);

    cvt_bf16_kernel<<<2048, 256, 0, stream>>>(x, Wqkv, Wp, xb, Wqb, Wpb);
    rope_tab_kernel<<<1536, 256, 0, stream>>>(freqs, tab);
    qkv_gemm_kernel<<<2322, 256, 0, stream>>>(Wqb, xb, tab, Qb, Kb, Vb);
    attn_mfma_kernel<<<1728, 256, 0, stream>>>(Qb, Kb, Vb, Obf);
    proj_gemm_kernel<<<774, 256, 0, stream>>>(Wpb, Obf, bp, out);
}

// Round 13
// 262.581 us; speedup vs baseline: 1.1313x; 1.0118x over previous
//
#include <hip/hip_runtime.h>
#include <math.h>

#define DIM     768
#define NH      12
#define HD      64
#define NTOK    1025
#define BATCH   16
#define MTOT    (BATCH * NTOK)        // 16400
#define QKVD    (3 * DIM)             // 2304

typedef short  short8  __attribute__((ext_vector_type(8)));
typedef short  short4v __attribute__((ext_vector_type(4)));
typedef float  f32x4   __attribute__((ext_vector_type(4)));

typedef const __attribute__((address_space(1))) void gvoid_t;
typedef __attribute__((address_space(3)))       void lvoid_t;
typedef __attribute__((address_space(3)))       char lchar_t;
#define GLD16(gsrc, ldst) __builtin_amdgcn_global_load_lds( \
    (gvoid_t*)(gsrc), (lvoid_t*)(ldst), 16, 0, 0)

static __device__ __forceinline__ unsigned int f2bf(float f) {
    unsigned int u = __float_as_uint(f);
    u += 0x7FFFu + ((u >> 16) & 1u);      // RNE
    return u >> 16;
}

// ------------------------------------------------------------------
// Kernel 0: fp32 -> bf16 conversion of x, W_qkv, W_proj
// ------------------------------------------------------------------
__device__ __forceinline__ void cvt8(const float* __restrict__ src,
                                     unsigned short* __restrict__ dst, int i) {
    float4 a = *(const float4*)(src + (size_t)i*8);
    float4 b = *(const float4*)(src + (size_t)i*8 + 4);
    uint4 pk;
    pk.x = f2bf(a.x) | (f2bf(a.y) << 16);
    pk.y = f2bf(a.z) | (f2bf(a.w) << 16);
    pk.z = f2bf(b.x) | (f2bf(b.y) << 16);
    pk.w = f2bf(b.z) | (f2bf(b.w) << 16);
    *(uint4*)(dst + (size_t)i*8) = pk;
}

__global__ __launch_bounds__(256) void cvt_bf16_kernel(
    const float* __restrict__ x, const float* __restrict__ Wq,
    const float* __restrict__ Wp,
    unsigned short* __restrict__ xb, unsigned short* __restrict__ Wqb,
    unsigned short* __restrict__ Wpb)
{
    const int stride = gridDim.x * blockDim.x;
    const int tid = blockIdx.x * blockDim.x + threadIdx.x;
    for (int i = tid; i < MTOT*DIM/8;  i += stride) cvt8(x,  xb,  i);
    for (int i = tid; i < QKVD*DIM/8;  i += stride) cvt8(Wq, Wqb, i);
    for (int i = tid; i < DIM*DIM/8;   i += stride) cvt8(Wp, Wpb, i);
}

// ------------------------------------------------------------------
// Kernel 0b: RoPE cos/sin table  [h][n1][pair] float2, 393216 entries
// ------------------------------------------------------------------
__global__ __launch_bounds__(256) void rope_tab_kernel(
    const float* __restrict__ freqs, float2* __restrict__ tab)
{
    const int gid = blockIdx.x * 256 + threadIdx.x;     // < 393216
    const int p  = gid & 31;
    const int n1 = (gid >> 5) & 1023;
    const int h  = gid >> 15;
    const float tx = (float)(n1 & 31), ty = (float)(n1 >> 5);
    const float ang = tx * freqs[h*32 + p] + ty * freqs[384 + h*32 + p];
    float s, c;
    sincosf(ang, &s, &c);
    tab[gid] = make_float2(c, s);
}

// ------------------------------------------------------------------
// Shared bf16 MFMA GEMM core: C[feat][tok] = W[feat][k] * X[tok][k]^T
// K=768, tile 128x128, BK=64, 256 threads (4 waves 2x2, each 64x64).
// ------------------------------------------------------------------
__device__ __forceinline__ void gemm_core(
    const unsigned short* __restrict__ Wb,
    const unsigned short* __restrict__ Xb,
    int D0, int T0, int maxXrow,
    short* Ws, short* Xs, f32x4 acc[4][4], int tid)
{
    const int lane = tid & 63;
    const int wu   = __builtin_amdgcn_readfirstlane(tid >> 6);
    const int wr   = wu >> 1, wc = wu & 1;
    const int l4   = lane >> 4, l15 = lane & 15;

    const int srow = lane >> 3;
    const int schk = (lane & 7) ^ srow;
    const unsigned short* wsrc[4];
    const unsigned short* xsrc[4];
#pragma unroll
    for (int i = 0; i < 4; ++i) {
        int r = wu*32 + i*8 + srow;
        wsrc[i] = Wb + (size_t)(D0 + r) * DIM + schk*8;
        int xr = T0 + r; if (xr > maxXrow) xr = maxXrow;
        xsrc[i] = Xb + (size_t)xr * DIM + schk*8;
    }

    for (int kt = 0; kt < DIM/64; ++kt) {
        __syncthreads();
#pragma unroll
        for (int i = 0; i < 4; ++i) {
            GLD16(wsrc[i] + kt*64, &Ws[(wu*4 + i) * 512]);
            GLD16(xsrc[i] + kt*64, &Xs[(wu*4 + i) * 512]);
        }
        __syncthreads();

        short8 wf[4][2], xf[4][2];
#pragma unroll
        for (int f = 0; f < 4; ++f) {
            const int rw = wr*64 + f*16 + l15;
            const int rx = wc*64 + f*16 + l15;
#pragma unroll
            for (int kf = 0; kf < 2; ++kf) {
                wf[f][kf] = *(const short8*)&Ws[rw*64 + (((kf*4 + l4) ^ (rw & 7)) << 3)];
                xf[f][kf] = *(const short8*)&Xs[rx*64 + (((kf*4 + l4) ^ (rx & 7)) << 3)];
            }
        }
        __builtin_amdgcn_s_setprio(1);
#pragma unroll
        for (int kf = 0; kf < 2; ++kf)
#pragma unroll
            for (int fm = 0; fm < 4; ++fm)
#pragma unroll
                for (int fn = 0; fn < 4; ++fn)
                    acc[fm][fn] = __builtin_amdgcn_mfma_f32_16x16x32_bf16(
                        wf[fm][kf], xf[fn][kf], acc[fm][fn], 0, 0, 0);
        __builtin_amdgcn_s_setprio(0);
    }
}

// ------------------------------------------------------------------
// Kernel 1: QKV GEMM + fused RoPE (table), bf16 out to Q/K/V (B,H,N,64)
// Q pre-scaled by scale*log2(e). 1D grid 2322, XCD-chunked so all 18
// D0-blocks of one token panel land on one XCD (x-panel L2 reuse).
// ------------------------------------------------------------------
__global__ __launch_bounds__(256) void qkv_gemm_kernel(
    const unsigned short* __restrict__ Wqb, const unsigned short* __restrict__ xb,
    const float2* __restrict__ tab,
    unsigned short* __restrict__ Qb, unsigned short* __restrict__ Kb,
    unsigned short* __restrict__ Vb)
{
    __shared__ __align__(16) short Ws[128*64];
    __shared__ __align__(16) short Xs[128*64];
    f32x4 acc[4][4] = {};
    const int tid = threadIdx.x;

    // bijective XCD swizzle: 2322 = 18 D0 x 129 T0-groups
    const int dd0 = blockIdx.x;
    int xc, j;
    if (dd0 >= 2304) { xc = 0; j = 288 + (dd0 - 2304); }
    else             { xc = dd0 & 7; j = dd0 >> 3; }
    const int D0 = (j % 18) * 128;
    const int T0 = (xc + 8 * (j / 18)) * 128;

    gemm_core(Wqb, xb, D0, T0, MTOT - 1, Ws, Xs, acc, tid);

    const int lane = tid & 63;
    const int wu = tid >> 6, wr = wu >> 1, wc = wu & 1;
    const int l4 = lane >> 4, l15 = lane & 15;
    const int which = D0 / DIM;
    unsigned short* dst = (which == 0) ? Qb : (which == 1) ? Kb : Vb;
    const float qs = (which == 0) ? 0.125f * 1.44269504089f : 1.f;

    unsigned bArr[4], nArr[4];
    bool vArr[4];
#pragma unroll
    for (int fn = 0; fn < 4; ++fn) {
        unsigned m = T0 + wc*64 + fn*16 + l15;
        vArr[fn] = m < MTOT;
        bArr[fn] = m / NTOK;
        nArr[fn] = m - bArr[fn]*NTOK;
    }
#pragma unroll
    for (int fm = 0; fm < 4; ++fm) {
        const int hcol = (D0 % DIM) + wr*64 + fm*16 + l4*4;
        const int h = hcol >> 6, dd = hcol & 63;
        const int p0 = dd >> 1;                    // even
#pragma unroll
        for (int fn = 0; fn < 4; ++fn) {
            if (!vArr[fn]) continue;
            f32x4 a = acc[fm][fn];
            const int n = nArr[fn];
            if (which < 2) {                       // RoPE on Q,K (not CLS)
                int n1 = n > 0 ? n - 1 : 0;
                float4 cs = *(const float4*)&tab[(size_t)(h*1024 + n1)*32 + p0];
                if (n == 0) cs = make_float4(1.f, 0.f, 1.f, 0.f);
                float e0 = a[0], od0 = a[1], e1 = a[2], od1 = a[3];
                a[0] = e0*cs.x - od0*cs.y;  a[1] = e0*cs.y + od0*cs.x;
                a[2] = e1*cs.z - od1*cs.w;  a[3] = e1*cs.w + od1*cs.z;
            }
            uint2 pk;
            pk.x = f2bf(a[0]*qs) | (f2bf(a[1]*qs) << 16);
            pk.y = f2bf(a[2]*qs) | (f2bf(a[3]*qs) << 16);
            *(uint2*)&dst[((size_t)(bArr[fn]*NH + h)*NTOK + n)*HD + dd] = pk;
        }
    }
}

// ------------------------------------------------------------------
// Kernel 2: bf16 MFMA flash attention (R12 base). NEW: softmax
// denominator computed on the MFMA pipe via lacc = mfma(ones, P-frag)
// (C[i][q] = sum_tok P[tok][q] for all i; lane col = l15 = q), deleting
// the 32 VALU adds/tile and the epilogue cross-lane reduce.
// ------------------------------------------------------------------
__global__ __launch_bounds__(256) void attn_mfma_kernel(
    const unsigned short* __restrict__ Qb,
    const unsigned short* __restrict__ Kb,
    const unsigned short* __restrict__ Vb,
    unsigned short* __restrict__ Obf)
{
    __shared__ __align__(16) char KsR[2][8192];   // [tok][64d], chunk^(tok&7)
    __shared__ __align__(16) char VtR[2][8192];   // [T=16][D=4][t=4][dd=16] bf16
    __shared__ __align__(16) char PsR[4][4096];   // per wave [32q][64tok], swz

    const int tid  = threadIdx.x;
    const int lane = tid & 63;
    const int w    = __builtin_amdgcn_readfirstlane(tid >> 6);
    const int l4   = lane >> 4, l15 = lane & 15, l7 = lane & 7;

    const int d    = blockIdx.x;
    const int xcd  = d & 7;
    const int s    = d >> 3;                 // 0..215
    const int bh   = xcd * 24 + s / 9;
    const int q0   = (s % 9) * 128;
    const size_t base = (size_t)bh * NTOK * HD;

    // Q frags (pre-scaled by scale*log2e)
    short8 qf[2][2];
#pragma unroll
    for (int qg = 0; qg < 2; ++qg) {
        int qr = q0 + w*32 + qg*16 + l15;
        int qrc = qr < NTOK ? qr : NTOK - 1;
        qf[qg][0] = *(const short8*)(Qb + base + (size_t)qrc*HD + l4*8);
        qf[qg][1] = *(const short8*)(Qb + base + (size_t)qrc*HD + 32 + l4*8);
    }

    const short ONE = (short)0x3F80;             // bf16 1.0
    const short8 ones = {ONE, ONE, ONE, ONE, ONE, ONE, ONE, ONE};

    f32x4 oA[4] = {}, oB[4] = {};          // O^T: row=d (l4,r), col=q (l15)
    f32x4 laccA = {}, laccB = {};          // l via mfma(ones, P)

    // K staging params
    const int ktokb = tid >> 3;                  // 0..31
    const int kchk  = tid & 7;
    // V staging params: chunk c -> (T,D,t,h8) subtile source
    const int c0 = tid, c1 = tid + 256;
    const int vt0 = ((c0 >> 5) << 2) | ((c0 >> 1) & 3);   // tile-local tok
    const int vt1 = ((c1 >> 5) << 2) | ((c1 >> 1) & 3);
    const int vo0 = (((c0 >> 3) & 3) << 4) | ((c0 & 1) << 3); // d offset
    const int vo1 = (((c1 >> 3) & 3) << 4) | ((c1 & 1) << 3);
    char* Pw = &PsR[w][0];

    // ---- prologue: stage tile 0 (K + V, all GLD) ----
#pragma unroll
    for (int i = 0; i < 2; ++i) {
        int tok = ktokb + i*32;
        int sc = kchk ^ (tok & 7);
        GLD16(Kb + base + (size_t)tok*HD + sc*8, &KsR[0][w*1024 + i*4096]);
    }
    GLD16(Vb + base + (size_t)vt0*HD + vo0, &VtR[0][w*1024]);
    GLD16(Vb + base + (size_t)vt1*HD + vo1, &VtR[0][4096 + w*1024]);

    for (int kt = 0; kt < 17; ++kt) {
        const int buf = kt & 1;
        __syncthreads();   // tile kt staged & visible (drains all GLDs)

        if (kt < 16) {
            const int nb = buf ^ 1;
#pragma unroll
            for (int i = 0; i < 2; ++i) {
                int tok = ktokb + i*32;
                int gk = (kt+1)*64 + tok; if (gk > NTOK-1) gk = NTOK-1;
                int sc = kchk ^ (tok & 7);
                GLD16(Kb + base + (size_t)gk*HD + sc*8, &KsR[nb][w*1024 + i*4096]);
            }
            int g0 = (kt+1)*64 + vt0; if (g0 > NTOK-1) g0 = NTOK-1;
            int g1 = (kt+1)*64 + vt1; if (g1 > NTOK-1) g1 = NTOK-1;
            GLD16(Vb + base + (size_t)g0*HD + vo0, &VtR[nb][w*1024]);
            GLD16(Vb + base + (size_t)g1*HD + vo1, &VtR[nb][4096 + w*1024]);
        }

        // ---- S^T = K @ Q^T  (lane: q = l15, tok = tg*16 + l4*4 + r) ----
        f32x4 sA[4] = {}, sB[4] = {};
        __builtin_amdgcn_s_setprio(1);
#pragma unroll
        for (int tg = 0; tg < 4; ++tg) {
            const int row = tg*16 + l15;
            short8 ka0 = *(const short8*)(&KsR[buf][0] + row*128 + ((l4 ^ l7) << 4));
            short8 ka1 = *(const short8*)(&KsR[buf][0] + row*128 + (((4 + l4) ^ l7) << 4));
            sA[tg] = __builtin_amdgcn_mfma_f32_16x16x32_bf16(ka0, qf[0][0], sA[tg], 0,0,0);
            sA[tg] = __builtin_amdgcn_mfma_f32_16x16x32_bf16(ka1, qf[0][1], sA[tg], 0,0,0);
            sB[tg] = __builtin_amdgcn_mfma_f32_16x16x32_bf16(ka0, qf[1][0], sB[tg], 0,0,0);
            sB[tg] = __builtin_amdgcn_mfma_f32_16x16x32_bf16(ka1, qf[1][1], sB[tg], 0,0,0);
        }
        __builtin_amdgcn_s_setprio(0);

        // ---- p = exp2(s); mask only last tile (p=0 protects clamped V) ----
        float pA[16], pB[16];
        if (kt == 16) {
#pragma unroll
            for (int tg = 0; tg < 4; ++tg)
#pragma unroll
                for (int r = 0; r < 4; ++r) {
                    int tok = 1024 + tg*16 + l4*4 + r;
                    float sa = (tok > 1024) ? -3e38f : sA[tg][r];
                    float sb = (tok > 1024) ? -3e38f : sB[tg][r];
                    pA[tg*4+r] = __builtin_exp2f(sa);
                    pB[tg*4+r] = __builtin_exp2f(sb);
                }
        } else {
#pragma unroll
            for (int tg = 0; tg < 4; ++tg)
#pragma unroll
                for (int r = 0; r < 4; ++r) {
                    pA[tg*4+r] = __builtin_exp2f(sA[tg][r]);
                    pB[tg*4+r] = __builtin_exp2f(sB[tg][r]);
                }
        }

        // ---- P -> LDS (packed bf16 pairs, b64 writes, swizzled) ----
#pragma unroll
        for (int tg = 0; tg < 4; ++tg) {
            unsigned k0a, k1a, k0b, k1b;
            asm volatile("v_cvt_pk_bf16_f32 %0, %1, %2" : "=v"(k0a) : "v"(pA[tg*4+0]), "v"(pA[tg*4+1]));
            asm volatile("v_cvt_pk_bf16_f32 %0, %1, %2" : "=v"(k1a) : "v"(pA[tg*4+2]), "v"(pA[tg*4+3]));
            asm volatile("v_cvt_pk_bf16_f32 %0, %1, %2" : "=v"(k0b) : "v"(pB[tg*4+0]), "v"(pB[tg*4+1]));
            asm volatile("v_cvt_pk_bf16_f32 %0, %1, %2" : "=v"(k1b) : "v"(pB[tg*4+2]), "v"(pB[tg*4+3]));
            const int chk = (((tg*2 + (l4 >> 1)) ^ l7) << 4) + (l4 & 1)*8;
            *(uint2*)(Pw + l15*128      + chk) = make_uint2(k0a, k1a);
            *(uint2*)(Pw + (16+l15)*128 + chk) = make_uint2(k0b, k1b);
        }
        __builtin_amdgcn_wave_barrier();

        const short8 pf00 = *(const short8*)(Pw + l15*128      + ((l4 ^ l7) << 4));
        const short8 pf01 = *(const short8*)(Pw + l15*128      + (((4+l4) ^ l7) << 4));
        const short8 pf10 = *(const short8*)(Pw + (16+l15)*128 + ((l4 ^ l7) << 4));
        const short8 pf11 = *(const short8*)(Pw + (16+l15)*128 + (((4+l4) ^ l7) << 4));

        // ---- l += ones @ P on the MFMA pipe (replaces 32 VALU adds) ----
        __builtin_amdgcn_s_setprio(1);
        laccA = __builtin_amdgcn_mfma_f32_16x16x32_bf16(ones, pf00, laccA, 0,0,0);
        laccA = __builtin_amdgcn_mfma_f32_16x16x32_bf16(ones, pf01, laccA, 0,0,0);
        laccB = __builtin_amdgcn_mfma_f32_16x16x32_bf16(ones, pf10, laccB, 0,0,0);
        laccB = __builtin_amdgcn_mfma_f32_16x16x32_bf16(ones, pf11, laccB, 0,0,0);
        __builtin_amdgcn_s_setprio(0);

        // ---- O^T += V^T @ P via hardware transpose reads ----
        const unsigned trb = (unsigned)(unsigned long long)
            (lchar_t*)(&VtR[buf][0] + (l4 << 10) + (l15 << 3));
        short4v r0a, r0b, r1a, r1b, r2a, r2b, r3a, r3b;

        // toks 0..31 (half 0): offset = dg*128 + c*512
        asm volatile(
            "ds_read_b64_tr_b16 %0, %8 offset:0\n\t"
            "ds_read_b64_tr_b16 %1, %8 offset:512\n\t"
            "ds_read_b64_tr_b16 %2, %8 offset:128\n\t"
            "ds_read_b64_tr_b16 %3, %8 offset:640\n\t"
            "ds_read_b64_tr_b16 %4, %8 offset:256\n\t"
            "ds_read_b64_tr_b16 %5, %8 offset:768\n\t"
            "ds_read_b64_tr_b16 %6, %8 offset:384\n\t"
            "ds_read_b64_tr_b16 %7, %8 offset:896\n\t"
            "s_waitcnt lgkmcnt(0)"
            : "=&v"(r0a), "=&v"(r0b), "=&v"(r1a), "=&v"(r1b),
              "=&v"(r2a), "=&v"(r2b), "=&v"(r3a), "=&v"(r3b)
            : "v"(trb) : "memory");
        __builtin_amdgcn_sched_barrier(0);
        {
            short8 v0 = __builtin_shufflevector(r0a, r0b, 0,1,2,3,4,5,6,7);
            short8 v1 = __builtin_shufflevector(r1a, r1b, 0,1,2,3,4,5,6,7);
            short8 v2 = __builtin_shufflevector(r2a, r2b, 0,1,2,3,4,5,6,7);
            short8 v3 = __builtin_shufflevector(r3a, r3b, 0,1,2,3,4,5,6,7);
            __builtin_amdgcn_s_setprio(1);
            oA[0] = __builtin_amdgcn_mfma_f32_16x16x32_bf16(v0, pf00, oA[0], 0,0,0);
            oB[0] = __builtin_amdgcn_mfma_f32_16x16x32_bf16(v0, pf10, oB[0], 0,0,0);
            oA[1] = __builtin_amdgcn_mfma_f32_16x16x32_bf16(v1, pf00, oA[1], 0,0,0);
            oB[1] = __builtin_amdgcn_mfma_f32_16x16x32_bf16(v1, pf10, oB[1], 0,0,0);
            oA[2] = __builtin_amdgcn_mfma_f32_16x16x32_bf16(v2, pf00, oA[2], 0,0,0);
            oB[2] = __builtin_amdgcn_mfma_f32_16x16x32_bf16(v2, pf10, oB[2], 0,0,0);
            oA[3] = __builtin_amdgcn_mfma_f32_16x16x32_bf16(v3, pf00, oA[3], 0,0,0);
            oB[3] = __builtin_amdgcn_mfma_f32_16x16x32_bf16(v3, pf10, oB[3], 0,0,0);
            __builtin_amdgcn_s_setprio(0);
        }
        // toks 32..63 (half 1): offsets + 4096
        asm volatile(
            "ds_read_b64_tr_b16 %0, %8 offset:4096\n\t"
            "ds_read_b64_tr_b16 %1, %8 offset:4608\n\t"
            "ds_read_b64_tr_b16 %2, %8 offset:4224\n\t"
            "ds_read_b64_tr_b16 %3, %8 offset:4736\n\t"
            "ds_read_b64_tr_b16 %4, %8 offset:4352\n\t"
            "ds_read_b64_tr_b16 %5, %8 offset:4864\n\t"
            "ds_read_b64_tr_b16 %6, %8 offset:4480\n\t"
            "ds_read_b64_tr_b16 %7, %8 offset:4992\n\t"
            "s_waitcnt lgkmcnt(0)"
            : "=&v"(r0a), "=&v"(r0b), "=&v"(r1a), "=&v"(r1b),
              "=&v"(r2a), "=&v"(r2b), "=&v"(r3a), "=&v"(r3b)
            : "v"(trb) : "memory");
        __builtin_amdgcn_sched_barrier(0);
        {
            short8 v0 = __builtin_shufflevector(r0a, r0b, 0,1,2,3,4,5,6,7);
            short8 v1 = __builtin_shufflevector(r1a, r1b, 0,1,2,3,4,5,6,7);
            short8 v2 = __builtin_shufflevector(r2a, r2b, 0,1,2,3,4,5,6,7);
            short8 v3 = __builtin_shufflevector(r3a, r3b, 0,1,2,3,4,5,6,7);
            __builtin_amdgcn_s_setprio(1);
            oA[0] = __builtin_amdgcn_mfma_f32_16x16x32_bf16(v0, pf01, oA[0], 0,0,0);
            oB[0] = __builtin_amdgcn_mfma_f32_16x16x32_bf16(v0, pf11, oB[0], 0,0,0);
            oA[1] = __builtin_amdgcn_mfma_f32_16x16x32_bf16(v1, pf01, oA[1], 0,0,0);
            oB[1] = __builtin_amdgcn_mfma_f32_16x16x32_bf16(v1, pf11, oB[1], 0,0,0);
            oA[2] = __builtin_amdgcn_mfma_f32_16x16x32_bf16(v2, pf01, oA[2], 0,0,0);
            oB[2] = __builtin_amdgcn_mfma_f32_16x16x32_bf16(v2, pf11, oB[2], 0,0,0);
            oA[3] = __builtin_amdgcn_mfma_f32_16x16x32_bf16(v3, pf01, oA[3], 0,0,0);
            oB[3] = __builtin_amdgcn_mfma_f32_16x16x32_bf16(v3, pf11, oB[3], 0,0,0);
            __builtin_amdgcn_s_setprio(0);
        }
    }

    // ---- epilogue: l is lane-local in lacc (all 4 rows equal) ----
    const float liA = 1.f / laccA[0];
    const float liB = 1.f / laccB[0];
    const int b = bh / NH, h = bh % NH;
    const int qA = q0 + w*32 + l15;
    const int qB = qA + 16;
    if (qA < NTOK) {
        unsigned short* p = Obf + ((size_t)b*NTOK + qA)*DIM + h*HD + l4*4;
#pragma unroll
        for (int dg = 0; dg < 4; ++dg) {
            uint2 pk;
            pk.x = f2bf(oA[dg][0]*liA) | (f2bf(oA[dg][1]*liA) << 16);
            pk.y = f2bf(oA[dg][2]*liA) | (f2bf(oA[dg][3]*liA) << 16);
            *(uint2*)(p + dg*16) = pk;
        }
    }
    if (qB < NTOK) {
        unsigned short* p = Obf + ((size_t)b*NTOK + qB)*DIM + h*HD + l4*4;
#pragma unroll
        for (int dg = 0; dg < 4; ++dg) {
            uint2 pk;
            pk.x = f2bf(oB[dg][0]*liB) | (f2bf(oB[dg][1]*liB) << 16);
            pk.y = f2bf(oB[dg][2]*liB) | (f2bf(oB[dg][3]*liB) << 16);
            *(uint2*)(p + dg*16) = pk;
        }
    }
}

// ------------------------------------------------------------------
// Kernel 3: proj GEMM (feat=768, tok=16400), fp32 out + bias.
// 1D grid 774, XCD-chunked (6 D0-blocks per token panel on one XCD).
// ------------------------------------------------------------------
__global__ __launch_bounds__(256) void proj_gemm_kernel(
    const unsigned short* __restrict__ Wpb, const unsigned short* __restrict__ Obf,
    const float* __restrict__ bp, float* __restrict__ out)
{
    __shared__ __align__(16) short Ws[128*64];
    __shared__ __align__(16) short Xs[128*64];
    f32x4 acc[4][4] = {};
    const int tid = threadIdx.x;

    // bijective XCD swizzle: 774 = 6 D0 x 129 T0-groups
    const int dd0 = blockIdx.x;
    int xc, j;
    if (dd0 >= 768) { xc = 0; j = 96 + (dd0 - 768); }
    else            { xc = dd0 & 7; j = dd0 >> 3; }
    const int D0 = (j % 6) * 128;
    const int T0 = (xc + 8 * (j / 6)) * 128;

    gemm_core(Wpb, Obf, D0, T0, MTOT - 1, Ws, Xs, acc, tid);

    const int lane = tid & 63;
    const int wu = tid >> 6, wr = wu >> 1, wc = wu & 1;
    const int l4 = lane >> 4, l15 = lane & 15;

    unsigned mArr[4];
    bool vArr[4];
#pragma unroll
    for (int fn = 0; fn < 4; ++fn) {
        unsigned m = T0 + wc*64 + fn*16 + l15;
        mArr[fn] = m;
        vArr[fn] = m < MTOT;
    }
#pragma unroll
    for (int fm = 0; fm < 4; ++fm) {
        const int nG = D0 + wr*64 + fm*16 + l4*4;
        const float4 bias = *(const float4*)&bp[nG];
#pragma unroll
        for (int fn = 0; fn < 4; ++fn) {
            if (!vArr[fn]) continue;
            f32x4 a = acc[fm][fn];
            float4 v = make_float4(a[0]+bias.x, a[1]+bias.y, a[2]+bias.z, a[3]+bias.w);
            *(float4*)&out[(size_t)mArr[fn]*DIM + nG] = v;
        }
    }
}

extern "C" void kernel_launch(void* const* d_in, const int* in_sizes, int n_in,
                              void* d_out, int out_size, void* d_ws, size_t ws_size,
                              hipStream_t stream)
{
    const float* x     = (const float*)d_in[0];
    const float* Wqkv  = (const float*)d_in[1];
    const float* Wp    = (const float*)d_in[2];
    const float* bp    = (const float*)d_in[3];
    const float* freqs = (const float*)d_in[4];
    float* out = (float*)d_out;

    const size_t SZ = (size_t)BATCH * NH * NTOK * HD;  // 12,595,200
    unsigned short* Qb  = (unsigned short*)d_ws;
    unsigned short* Kb  = Qb + SZ;
    unsigned short* Vb  = Kb + SZ;
    unsigned short* Obf = Vb + SZ;
    unsigned short* xb  = Obf + SZ;
    unsigned short* Wqb = xb + SZ;
    unsigned short* Wpb = Wqb + (size_t)QKVD * DIM;
    float2*         tab = (float2*)(Wpb + (size_t)DIM * DIM);

    cvt_bf16_kernel<<<2048, 256, 0, stream>>>(x, Wqkv, Wp, xb, Wqb, Wpb);
    rope_tab_kernel<<<1536, 256, 0, stream>>>(freqs, tab);
    qkv_gemm_kernel<<<2322, 256, 0, stream>>>(Wqb, xb, tab, Qb, Kb, Vb);
    attn_mfma_kernel<<<1728, 256, 0, stream>>>(Qb, Kb, Vb, Obf);
    proj_gemm_kernel<<<774, 256, 0, stream>>>(Wpb, Obf, bp, out);
}